// Round 9
// baseline (398.047 us; speedup 1.0000x reference)
//
#include <hip/hip_runtime.h>
#include <math.h>

typedef __bf16 bf16_t;
typedef __bf16 bf16x8 __attribute__((ext_vector_type(8)));
typedef __bf16 bf16x4 __attribute__((ext_vector_type(4)));
typedef float  f32x4  __attribute__((ext_vector_type(4)));
typedef _Float16 f16_t;
typedef _Float16 f16x4 __attribute__((ext_vector_type(4)));
typedef __fp16 hf16x2 __attribute__((ext_vector_type(2)));

static constexpr float ATT_SCALE = 0.15811388300841897f; // 40^-0.5
static constexpr float SC2 = 0.22811031f;                // ATT_SCALE * log2(e)
static constexpr float LOG2E = 1.4426950408889634f;

__device__ __forceinline__ bf16_t f2b(float f) {
  unsigned u = __float_as_uint(f);
  u = (u + 0x7fffu + ((u >> 16) & 1u)) >> 16;   // RNE
  unsigned short s = (unsigned short)u;
  bf16_t r;
  *(unsigned short*)&r = s;
  return r;
}
__device__ __forceinline__ float b2f(bf16_t b) {
  unsigned short s = *(const unsigned short*)&b;
  return __uint_as_float(((unsigned)s) << 16);
}
__device__ __forceinline__ void sto(float v, float* p)  { *p = v; }
__device__ __forceinline__ void sto(float v, bf16_t* p) { *p = f2b(v); }
__device__ __forceinline__ unsigned pkh2(float a, float b) {
  hf16x2 h = __builtin_amdgcn_cvt_pkrtz(a, b);
  return *(unsigned*)&h;
}

// =========================== weight repack ===========================
__global__ __launch_bounds__(256) void prep_kernel(
    const float* __restrict__ Wq1, const float* __restrict__ Wk1, const float* __restrict__ Wv1,
    const float* __restrict__ Wo1, const float* __restrict__ Wq2,
    const float* __restrict__ Wk2, const float* __restrict__ Wv2, const float* __restrict__ Wo2,
    const float* __restrict__ Wff1, const float* __restrict__ Wff2,
    const float* __restrict__ fam,
    bf16_t* __restrict__ wqkvt, bf16_t* __restrict__ wo1t, float* __restrict__ wkv2t,
    bf16_t* __restrict__ wo2t, bf16_t* __restrict__ wff1t, bf16_t* __restrict__ wff2t,
    bf16_t* __restrict__ wq2th, bf16_t* __restrict__ wq2tl,
    bf16_t* __restrict__ famh, bf16_t* __restrict__ faml)
{
  const int T1 = 960*320;
  const int T2 = T1 + 320*320;
  const int T3 = T2 + 768*640;
  const int T4 = T3 + 320*320;
  const int T5 = T4 + 2560*320;
  const int T6 = T5 + 320*1280;
  const int T7 = T6 + 320*320;
  const int T8 = T7 + 96*96;
  for (int i = blockIdx.x*256 + threadIdx.x; i < T8; i += gridDim.x*256) {
    if (i < T1) {
      int n = i / 320, k = i - n*320;
      float v = (n < 320) ? Wq1[k*320+n] * SC2
              : (n < 640) ? Wk1[k*320+n-320] : Wv1[k*320+n-640];
      wqkvt[i] = f2b(v);
    } else if (i < T2) {
      int e = i - T1; int n = e / 320, k = e - n*320;
      wo1t[e] = f2b(Wo1[k*320+n]);
    } else if (i < T3) {
      int e = i - T2; int n = e / 768, k = e - n*768;
      wkv2t[e] = (n < 320) ? Wk2[k*320+n] : Wv2[k*320+n-320];
    } else if (i < T4) {
      int e = i - T3; int n = e / 320, k = e - n*320;
      wo2t[e] = f2b(Wo2[k*320+n]);
    } else if (i < T5) {
      int e = i - T4; int n = e / 320, k = e - n*320;
      wff1t[e] = f2b(Wff1[(size_t)k*2560+n]);
    } else if (i < T6) {
      int e = i - T5; int n = e / 1280, k = e - n*1280;
      wff2t[e] = f2b(Wff2[k*320+n]);
    } else if (i < T7) {
      int e = i - T6; int n = e / 320, k = e - n*320;
      float v = Wq2[k*320+n];
      bf16_t h = f2b(v);
      wq2th[e] = h;
      wq2tl[e] = f2b(v - b2f(h));
    } else {
      int e = i - T7; int d = e / 96, k = e - d*96;
      float v = (d < 77 && k < 77) ? fam[d*77 + k] : 0.f;
      bf16_t h = f2b(v);
      famh[e] = h;
      faml[e] = f2b(v - b2f(h));
    }
  }
}

// =========================== LayerNorm ===========================
template<typename OT>
__global__ __launch_bounds__(256) void ln_kernel(
    const float* __restrict__ x, const float* __restrict__ g, const float* __restrict__ b,
    OT* __restrict__ out)
{
  const int lane = threadIdx.x & 63;
  const int row = blockIdx.x * 4 + (threadIdx.x >> 6);
  const float* xr = x + (size_t)row * 320;
  float v[5], s = 0.f, s2 = 0.f;
#pragma unroll
  for (int i = 0; i < 5; i++) { v[i] = xr[lane + i*64]; s += v[i]; s2 += v[i]*v[i]; }
#pragma unroll
  for (int o = 32; o; o >>= 1) { s += __shfl_xor(s, o); s2 += __shfl_xor(s2, o); }
  float mu = s * (1.f/320.f);
  float rs = rsqrtf(fmaxf(s2*(1.f/320.f) - mu*mu, 0.f) + 1e-5f);
#pragma unroll
  for (int i = 0; i < 5; i++) {
    int c = lane + i*64;
    sto((v[i]-mu)*rs*g[c] + b[c], &out[(size_t)row*320 + c]);
  }
}

// LayerNorm writing hi/lo bf16 split
__global__ __launch_bounds__(256) void ln2_split_kernel(
    const float* __restrict__ x, const float* __restrict__ g, const float* __restrict__ b,
    bf16_t* __restrict__ hi, bf16_t* __restrict__ lo)
{
  const int lane = threadIdx.x & 63;
  const int row = blockIdx.x * 4 + (threadIdx.x >> 6);
  const float* xr = x + (size_t)row * 320;
  float v[5], s = 0.f, s2 = 0.f;
#pragma unroll
  for (int i = 0; i < 5; i++) { v[i] = xr[lane + i*64]; s += v[i]; s2 += v[i]*v[i]; }
#pragma unroll
  for (int o = 32; o; o >>= 1) { s += __shfl_xor(s, o); s2 += __shfl_xor(s2, o); }
  float mu = s * (1.f/320.f);
  float rs = rsqrtf(fmaxf(s2*(1.f/320.f) - mu*mu, 0.f) + 1e-5f);
#pragma unroll
  for (int i = 0; i < 5; i++) {
    int c = lane + i*64;
    float y = (v[i]-mu)*rs*g[c] + b[c];
    bf16_t h = f2b(y);
    hi[(size_t)row*320 + c] = h;
    lo[(size_t)row*320 + c] = f2b(y - b2f(h));
  }
}

// =========================== kv2 dot-product GEMM ===========================
__global__ __launch_bounds__(256) void kv2_dot_kernel(
    const float* __restrict__ ctx, const float* __restrict__ wkv2t, float* __restrict__ kv2)
{
  const int gid = blockIdx.x*16 + (threadIdx.x >> 4);
  const int q = threadIdx.x & 15;
  const int m = gid / 640, n = gid - m*640;
  const float4* a = (const float4*)(ctx + (size_t)m*768);
  const float4* b = (const float4*)(wkv2t + (size_t)n*768);
  float acc = 0.f;
#pragma unroll
  for (int i = 0; i < 12; i++) {
    float4 av = a[i*16+q], bv = b[i*16+q];
    acc += av.x*bv.x + av.y*bv.y + av.z*bv.z + av.w*bv.w;
  }
#pragma unroll
  for (int o = 8; o; o >>= 1) acc += __shfl_xor(acc, o);
  if (q == 0) kv2[(size_t)m*640 + n] = acc;
}

// =========================== kv2 post: K2 hi/lo and V^T ===========================
__global__ __launch_bounds__(256) void kv2_post_kernel(
    const float* __restrict__ kv2, bf16_t* __restrict__ k2h, bf16_t* __restrict__ k2l,
    bf16_t* __restrict__ v2t)
{
  const int NK = 8*96*64;
  const int NV = 8*48*96;
  int i = blockIdx.x*256 + threadIdx.x;
  if (i < NK) {
    int h = i / (96*64), r = i - h*96*64, j = r >> 6, d = r & 63;
    float v = (j < 77 && d < 40) ? kv2[(size_t)j*640 + h*40 + d] : 0.f;
    bf16_t hh = f2b(v);
    k2h[i] = hh;
    k2l[i] = f2b(v - b2f(hh));
  } else if (i < NK + NV) {
    int e = i - NK;
    int h = e / (48*96), r = e - h*48*96, d = r / 96, j = r - d*96;
    v2t[e] = f2b((d < 40 && j < 77) ? kv2[(size_t)j*640 + 320 + h*40 + d] : 0.f);
  }
}

// =========================== V^T repack (self-attn): f16, 48 rows, row 40 = ones ===========================
__global__ __launch_bounds__(256) void repack_vt_kernel(
    const bf16_t* __restrict__ qkvb, f16_t* __restrict__ vtg)
{
  __shared__ f16_t T[64*44];
  const int tid = threadIdx.x;
  const int t0 = blockIdx.x * 64, h = blockIdx.y;
  for (int e = tid; e < 320; e += 256) {
    int t = e / 5, c8 = (e - t*5) * 8;
    bf16x8 v = *(const bf16x8*)(qkvb + (size_t)(t0+t)*960 + 640 + h*40 + c8);
    f16_t* dst = &T[t*44 + c8];
#pragma unroll
    for (int j = 0; j < 8; j++) dst[j] = (f16_t)b2f(v[j]);
  }
  __syncthreads();
  for (int e = tid; e < 320; e += 256) {
    int d = e >> 3, t8 = (e & 7) * 8;
    f16_t* dst = vtg + ((size_t)h*48 + d)*4096 + t0 + t8;
#pragma unroll
    for (int j = 0; j < 8; j++) dst[j] = T[(t8+j)*44 + d];
  }
  for (int e = tid; e < 512; e += 256) {
    int r = 40 + (e >> 6), t = e & 63;
    vtg[((size_t)h*48 + r)*4096 + t0 + t] = (r == 40) ? (f16_t)1.0f : (f16_t)0.0f;
  }
}

// =========================== bf16/f16 MFMA flash self-attention (v5) ===========================
// block = 64 q-rows x 1 head; 4 waves own disjoint 16-key slices of each 64-key tile.
// 4 K-splits (grid 2048 = 8 blocks/CU) for occupancy; 12 KB LDS (4-pass epilogue) so LDS
// doesn't cap blocks/CU; opart stored bf16. K prefetch; p in f16; denominator via V^T ones-row.
// grid (64, 8, 4).
__global__ __launch_bounds__(256, 4) void flash_self_kernel(
    const bf16_t* __restrict__ qkvb, const f16_t* __restrict__ vtg,
    bf16_t* __restrict__ opart, float* __restrict__ lpart)
{
  __shared__ float Red[3072];      // 12 KB
  const int tid = threadIdx.x;
  const int w = tid >> 6, lane = tid & 63;
  const int ln = lane & 15, qd = lane >> 4;
  const int h = blockIdx.y;
  const int q0 = blockIdx.x * 64;
  const int split = blockIdx.z;

  bf16x8 zero8 = {};
  bf16x8 bq[4][2];
#pragma unroll
  for (int nt = 0; nt < 4; nt++) {
    const bf16_t* qp = qkvb + (size_t)(q0 + nt*16 + ln)*960 + h*40;
    bq[nt][0] = *(const bf16x8*)(qp + qd*8);
    bq[nt][1] = (qd == 0) ? *(const bf16x8*)(qp + 32) : zero8;
  }

  f32x4 zero4 = {0.f,0.f,0.f,0.f};
  f32x4 oacc[3][4];                // [dt][nt]  O^T accum
#pragma unroll
  for (int a = 0; a < 3; a++)
#pragma unroll
    for (int b = 0; b < 4; b++) oacc[a][b] = zero4;

  const bf16_t* kbase = qkvb + 320 + h*40 + (size_t)(w*16 + ln)*960;
  const f16_t*  vrow  = vtg + (size_t)h*48*4096 + (size_t)ln*4096 + w*16 + qd*4;

  const bf16_t* kp0 = kbase + (size_t)(split*1024)*960;
  bf16x8 ka0 = *(const bf16x8*)(kp0 + qd*8);
  bf16x8 ka1 = (qd == 0) ? *(const bf16x8*)(kp0 + 32) : zero8;

  for (int kt = 0; kt < 16; kt++) {
    int k0 = split*1024 + kt*64;
    bf16x8 nka0 = zero8, nka1 = zero8;
    if (kt < 15) {
      const bf16_t* kpn = kbase + (size_t)(k0 + 64)*960;
      nka0 = *(const bf16x8*)(kpn + qd*8);
      if (qd == 0) nka1 = *(const bf16x8*)(kpn + 32);
    }

    f16x4 pb[4];
#pragma unroll
    for (int nt = 0; nt < 4; nt++) {
      f32x4 s = __builtin_amdgcn_mfma_f32_16x16x32_bf16(ka0, bq[nt][0], zero4, 0, 0, 0);
      s = __builtin_amdgcn_mfma_f32_16x16x32_bf16(ka1, bq[nt][1], s, 0, 0, 0);
      uint2 u;
      u.x = pkh2(__builtin_amdgcn_exp2f(s[0]), __builtin_amdgcn_exp2f(s[1]));
      u.y = pkh2(__builtin_amdgcn_exp2f(s[2]), __builtin_amdgcn_exp2f(s[3]));
      pb[nt] = *(f16x4*)&u;
    }
#pragma unroll
    for (int dt = 0; dt < 3; dt++) {
      f16x4 va = *(const f16x4*)(vrow + (size_t)dt*16*4096 + k0);
#pragma unroll
      for (int nt = 0; nt < 4; nt++)
        oacc[dt][nt] = __builtin_amdgcn_mfma_f32_16x16x16f16(va, pb[nt], oacc[dt][nt], 0, 0, 0);
    }
    ka0 = nka0;
    ka1 = nka1;
  }

  // ---- epilogue: 4 passes (one per q n-tile), cross-wave reduction via 12 KB LDS ----
  bf16_t* obase = opart + ((size_t)(split*8 + h)*4096 + q0)*40;
  const int lq = tid >> 4, dd = tid & 15;
  for (int nt = 0; nt < 4; nt++) {
    __syncthreads();
#pragma unroll
    for (int dt = 0; dt < 3; dt++)
      *(f32x4*)&Red[(w*3 + dt)*256 + ln*16 + qd*4] = oacc[dt][nt];
    __syncthreads();
#pragma unroll
    for (int i = 0; i < 3; i++) {
      int d = i*16 + dd;               // 0..47
      float v = Red[(0*3+i)*256 + lq*16 + dd]
              + Red[(1*3+i)*256 + lq*16 + dd]
              + Red[(2*3+i)*256 + lq*16 + dd]
              + Red[(3*3+i)*256 + lq*16 + dd];
      if (d < 40)      obase[(size_t)(nt*16 + lq)*40 + d] = f2b(v);
      else if (d == 40) lpart[(size_t)(split*8 + h)*4096 + q0 + nt*16 + lq] = v;
    }
  }
}

// =========================== merge K-split partials (4 splits, bf16 opart) ===========================
__global__ __launch_bounds__(256) void merge_o1_kernel(
    const bf16_t* __restrict__ op, const float* __restrict__ lp, bf16_t* __restrict__ o1a)
{
  int i = blockIdx.x*256 + threadIdx.x;
  int q = i / 320, c = i - q*320;
  int h = c / 40, d = c - h*40;
  size_t base = ((size_t)h*4096 + q)*40 + d;
  int lq = h*4096 + q;
  float l = lp[lq] + lp[32768 + lq] + lp[65536 + lq] + lp[98304 + lq];
  float o = b2f(op[base]) + b2f(op[base + 1310720])
          + b2f(op[base + 2621440]) + b2f(op[base + 3932160]);
  o1a[i] = f2b(o / l);
}

// =========================== cross-attention (all-MFMA, single-pass, no barriers) ===========================
__global__ __launch_bounds__(256) void attn_cross_kernel(
    const float* __restrict__ q2, const bf16_t* __restrict__ k2h, const bf16_t* __restrict__ k2l,
    const bf16_t* __restrict__ famh, const bf16_t* __restrict__ faml,
    const bf16_t* __restrict__ v2t, const int* __restrict__ use_fca,
    bf16_t* __restrict__ o2)
{
  __shared__ bf16_t SMh[4][16*96];
  __shared__ bf16_t SMl[4][16*96];
  __shared__ bf16_t PAs[4][16*96];
  const int tid = threadIdx.x;
  const int w = tid >> 6, lane = tid & 63;
  const int ln = lane & 15, qd = lane >> 4;
  const int h = blockIdx.y;
  const int q0 = blockIdx.x*64 + w*16;
  const int fca = use_fca[0];
  bf16_t* smh = SMh[w];
  bf16_t* sml = SMl[w];
  bf16_t* pa  = PAs[w];

  {
    bf16x4 z = {};
    int q = lane >> 2, c = 80 + (lane & 3)*4;
    *(bf16x4*)&smh[q*96 + c] = z;
    *(bf16x4*)&sml[q*96 + c] = z;
    *(bf16x4*)&pa [q*96 + c] = z;
  }

  bf16x8 zero8 = {};
  bf16x8 aqh0, aql0, aqh1 = zero8, aql1 = zero8;
  {
    const float* qp = q2 + (size_t)(q0 + ln)*320 + h*40;
    float4 v0 = *(const float4*)(qp + qd*8);
    float4 v1 = *(const float4*)(qp + qd*8 + 4);
    float qv[8] = {v0.x,v0.y,v0.z,v0.w,v1.x,v1.y,v1.z,v1.w};
#pragma unroll
    for (int i = 0; i < 8; i++) {
      bf16_t hh = f2b(qv[i]);
      aqh0[i] = hh; aql0[i] = f2b(qv[i] - b2f(hh));
    }
    if (qd == 0) {
      float4 u0 = *(const float4*)(qp + 32);
      float4 u1 = *(const float4*)(qp + 36);
      float uv[8] = {u0.x,u0.y,u0.z,u0.w,u1.x,u1.y,u1.z,u1.w};
#pragma unroll
      for (int i = 0; i < 8; i++) {
        bf16_t hh = f2b(uv[i]);
        aqh1[i] = hh; aql1[i] = f2b(uv[i] - b2f(hh));
      }
    }
  }

  f32x4 zero4 = {0.f,0.f,0.f,0.f};
  float ss[5][4];
#pragma unroll
  for (int nt = 0; nt < 5; nt++) {
    const bf16_t* kb = k2h + ((size_t)h*96 + nt*16 + ln)*64 + qd*8;
    const bf16_t* kl = k2l + ((size_t)h*96 + nt*16 + ln)*64 + qd*8;
    bf16x8 kh0 = *(const bf16x8*)kb;
    bf16x8 kh1 = *(const bf16x8*)(kb + 32);
    bf16x8 kl0 = *(const bf16x8*)kl;
    bf16x8 kl1 = *(const bf16x8*)(kl + 32);
    f32x4 s;
    s = __builtin_amdgcn_mfma_f32_16x16x32_bf16(aqh0, kl0, zero4, 0, 0, 0);
    s = __builtin_amdgcn_mfma_f32_16x16x32_bf16(aql0, kh0, s, 0, 0, 0);
    s = __builtin_amdgcn_mfma_f32_16x16x32_bf16(aqh0, kh0, s, 0, 0, 0);
    s = __builtin_amdgcn_mfma_f32_16x16x32_bf16(aqh1, kl1, s, 0, 0, 0);
    s = __builtin_amdgcn_mfma_f32_16x16x32_bf16(aql1, kh1, s, 0, 0, 0);
    s = __builtin_amdgcn_mfma_f32_16x16x32_bf16(aqh1, kh1, s, 0, 0, 0);
#pragma unroll
    for (int r = 0; r < 4; r++) {
      float sv = s[r] * ATT_SCALE;
      ss[nt][r] = sv;
      bf16_t hh = f2b(sv);
      smh[(qd*4 + r)*96 + nt*16 + ln] = hh;
      sml[(qd*4 + r)*96 + nt*16 + ln] = f2b(sv - b2f(hh));
    }
  }

  f32x4 facc[5];
#pragma unroll
  for (int nt = 0; nt < 5; nt++) facc[nt] = zero4;
#pragma unroll
  for (int c = 0; c < 3; c++) {
    bf16x8 sah = *(const bf16x8*)&smh[ln*96 + c*32 + qd*8];
    bf16x8 sal = *(const bf16x8*)&sml[ln*96 + c*32 + qd*8];
#pragma unroll
    for (int nt = 0; nt < 5; nt++) {
      bf16x8 fh8 = *(const bf16x8*)(famh + ((size_t)(nt*16 + ln))*96 + c*32 + qd*8);
      bf16x8 fl8 = *(const bf16x8*)(faml + ((size_t)(nt*16 + ln))*96 + c*32 + qd*8);
      facc[nt] = __builtin_amdgcn_mfma_f32_16x16x32_bf16(sah, fl8, facc[nt], 0, 0, 0);
      facc[nt] = __builtin_amdgcn_mfma_f32_16x16x32_bf16(sal, fh8, facc[nt], 0, 0, 0);
      facc[nt] = __builtin_amdgcn_mfma_f32_16x16x32_bf16(sah, fh8, facc[nt], 0, 0, 0);
    }
  }

  float pr[5][4];
  if (fca) {
    float fwv[5][4], fm[4];
#pragma unroll
    for (int nt = 0; nt < 5; nt++)
#pragma unroll
      for (int r = 0; r < 4; r++) fwv[nt][r] = fminf(fabsf(facc[nt][r]), 1.f);
#pragma unroll
    for (int r = 0; r < 4; r++) {
      float m = fmaxf(fmaxf(fwv[0][r], fwv[1][r]), fmaxf(fwv[2][r], fmaxf(fwv[3][r], fwv[4][r])));
#pragma unroll
      for (int o = 8; o; o >>= 1) m = fmaxf(m, __shfl_xor(m, o));
      fm[r] = m;
    }
#pragma unroll
    for (int nt = 0; nt < 5; nt++)
#pragma unroll
      for (int r = 0; r < 4; r++) {
        float lg = ss[nt][r] - ((fwv[nt][r] > 0.6f*(fm[r] + 1e-6f)) ? 0.f : 50.f);
        pr[nt][r] = __builtin_amdgcn_exp2f(lg * LOG2E);
      }
  } else {
#pragma unroll
    for (int nt = 0; nt < 5; nt++)
#pragma unroll
      for (int r = 0; r < 4; r++)
        pr[nt][r] = __builtin_amdgcn_exp2f(ss[nt][r] * LOG2E);
  }
  if (ln >= 13) {
#pragma unroll
    for (int r = 0; r < 4; r++) pr[4][r] = 0.f;
  }
  float l_[4] = {0.f,0.f,0.f,0.f};
#pragma unroll
  for (int nt = 0; nt < 5; nt++)
#pragma unroll
    for (int r = 0; r < 4; r++) {
      l_[r] += pr[nt][r];
      pa[(qd*4 + r)*96 + nt*16 + ln] = f2b(pr[nt][r]);
    }
#pragma unroll
  for (int r = 0; r < 4; r++)
#pragma unroll
    for (int o = 8; o; o >>= 1) l_[r] += __shfl_xor(l_[r], o);

  f32x4 oacc[3];
#pragma unroll
  for (int nt = 0; nt < 3; nt++) oacc[nt] = zero4;
#pragma unroll
  for (int c = 0; c < 3; c++) {
    bf16x8 paf = *(const bf16x8*)&pa[ln*96 + c*32 + qd*8];
#pragma unroll
    for (int nt = 0; nt < 3; nt++) {
      bf16x8 vb = *(const bf16x8*)(v2t + ((size_t)h*48 + nt*16 + ln)*96 + c*32 + qd*8);
      oacc[nt] = __builtin_amdgcn_mfma_f32_16x16x32_bf16(paf, vb, oacc[nt], 0, 0, 0);
    }
  }
  float inv[4];
#pragma unroll
  for (int r = 0; r < 4; r++) inv[r] = 1.f / l_[r];
#pragma unroll
  for (int nt = 0; nt < 3; nt++) {
    int d = nt*16 + ln;
    if (d < 40) {
#pragma unroll
      for (int r = 0; r < 4; r++)
        o2[(size_t)(q0 + qd*4 + r)*320 + h*40 + d] = f2b(oacc[nt][r]*inv[r]);
    }
  }
}

// =========================== bf16 MFMA GEMM 128x64: C = A[M][K] @ Bt[N][K]^T ===========================
template<int OUT_BF16>
__global__ __launch_bounds__(256) void gemm_bf16_kernel(
    const bf16_t* __restrict__ A, const bf16_t* __restrict__ Bt,
    const float* __restrict__ bias, const float* __restrict__ resid,
    void* __restrict__ Cout, int M, int N, int K)
{
  __shared__ bf16_t As[128][72];
  __shared__ bf16_t Bs[64][72];
  const int tid = threadIdx.x;
  const int m0 = blockIdx.x * 128, n0 = blockIdx.y * 64;
  const int w = tid >> 6, lane = tid & 63;
  const int wr = w >> 1, wc = w & 1;
  const int ln = lane & 15, qd = lane >> 4;
  f32x4 zero = {0.f, 0.f, 0.f, 0.f};
  f32x4 acc[4][2];
#pragma unroll
  for (int a = 0; a < 4; a++)
#pragma unroll
    for (int b = 0; b < 2; b++) acc[a][b] = zero;

  for (int k0 = 0; k0 < K; k0 += 64) {
    __syncthreads();
#pragma unroll
    for (int i = 0; i < 4; i++) {
      int vid = tid + i*256;
      int r = vid >> 3, c8 = (vid & 7) * 8;
      *(bf16x8*)&As[r][c8] = *(const bf16x8*)(A + (size_t)(m0+r)*K + k0 + c8);
    }
#pragma unroll
    for (int i = 0; i < 2; i++) {
      int vid = tid + i*256;
      int r = vid >> 3, c8 = (vid & 7) * 8;
      *(bf16x8*)&Bs[r][c8] = *(const bf16x8*)(Bt + (size_t)(n0+r)*K + k0 + c8);
    }
    __syncthreads();
#pragma unroll
    for (int c = 0; c < 2; c++) {
      bf16x8 af[4], bfr[2];
#pragma unroll
      for (int mt = 0; mt < 4; mt++)
        af[mt] = *(const bf16x8*)&As[wr*64 + mt*16 + ln][c*32 + qd*8];
#pragma unroll
      for (int nt = 0; nt < 2; nt++)
        bfr[nt] = *(const bf16x8*)&Bs[wc*32 + nt*16 + ln][c*32 + qd*8];
#pragma unroll
      for (int mt = 0; mt < 4; mt++)
#pragma unroll
        for (int nt = 0; nt < 2; nt++)
          acc[mt][nt] = __builtin_amdgcn_mfma_f32_16x16x32_bf16(af[mt], bfr[nt], acc[mt][nt], 0, 0, 0);
    }
  }
#pragma unroll
  for (int mt = 0; mt < 4; mt++)
#pragma unroll
    for (int nt = 0; nt < 2; nt++)
#pragma unroll
      for (int r = 0; r < 4; r++) {
        int gm = m0 + wr*64 + mt*16 + qd*4 + r;
        int gn = n0 + wc*32 + nt*16 + ln;
        float v = acc[mt][nt][r];
        if (bias)  v += bias[gn];
        if (resid) v += resid[(size_t)gm*N + gn];
        if (OUT_BF16) sto(v, &((bf16_t*)Cout)[(size_t)gm*N + gn]);
        else          sto(v, &((float*)Cout)[(size_t)gm*N + gn]);
      }
}

// =========================== bf16 MFMA GEMM 64x64 (2x block count for narrow-N GEMMs) ===========================
template<int OUT_BF16>
__global__ __launch_bounds__(256) void gemm_bf16_64_kernel(
    const bf16_t* __restrict__ A, const bf16_t* __restrict__ Bt,
    const float* __restrict__ bias, const float* __restrict__ resid,
    void* __restrict__ Cout, int M, int N, int K)
{
  __shared__ bf16_t As[64][72];
  __shared__ bf16_t Bs[64][72];
  const int tid = threadIdx.x;
  const int m0 = blockIdx.x * 64, n0 = blockIdx.y * 64;
  const int w = tid >> 6, lane = tid & 63;
  const int wr = w >> 1, wc = w & 1;
  const int ln = lane & 15, qd = lane >> 4;
  f32x4 zero = {0.f, 0.f, 0.f, 0.f};
  f32x4 acc[2][2];
#pragma unroll
  for (int a = 0; a < 2; a++)
#pragma unroll
    for (int b = 0; b < 2; b++) acc[a][b] = zero;

  for (int k0 = 0; k0 < K; k0 += 64) {
    __syncthreads();
#pragma unroll
    for (int i = 0; i < 2; i++) {
      int vid = tid + i*256;
      int r = vid >> 3, c8 = (vid & 7) * 8;
      *(bf16x8*)&As[r][c8] = *(const bf16x8*)(A + (size_t)(m0+r)*K + k0 + c8);
      *(bf16x8*)&Bs[r][c8] = *(const bf16x8*)(Bt + (size_t)(n0+r)*K + k0 + c8);
    }
    __syncthreads();
#pragma unroll
    for (int c = 0; c < 2; c++) {
      bf16x8 af[2], bfr[2];
#pragma unroll
      for (int mt = 0; mt < 2; mt++)
        af[mt] = *(const bf16x8*)&As[wr*32 + mt*16 + ln][c*32 + qd*8];
#pragma unroll
      for (int nt = 0; nt < 2; nt++)
        bfr[nt] = *(const bf16x8*)&Bs[wc*32 + nt*16 + ln][c*32 + qd*8];
#pragma unroll
      for (int mt = 0; mt < 2; mt++)
#pragma unroll
        for (int nt = 0; nt < 2; nt++)
          acc[mt][nt] = __builtin_amdgcn_mfma_f32_16x16x32_bf16(af[mt], bfr[nt], acc[mt][nt], 0, 0, 0);
    }
  }
#pragma unroll
  for (int mt = 0; mt < 2; mt++)
#pragma unroll
    for (int nt = 0; nt < 2; nt++)
#pragma unroll
      for (int r = 0; r < 4; r++) {
        int gm = m0 + wr*32 + mt*16 + qd*4 + r;
        int gn = n0 + wc*32 + nt*16 + ln;
        float v = acc[mt][nt][r];
        if (bias)  v += bias[gn];
        if (resid) v += resid[(size_t)gm*N + gn];
        if (OUT_BF16) sto(v, &((bf16_t*)Cout)[(size_t)gm*N + gn]);
        else          sto(v, &((float*)Cout)[(size_t)gm*N + gn]);
      }
}

// =========================== 3-term bf16 MFMA GEMM (fp32 emulation) ===========================
__global__ __launch_bounds__(256) void gemm3_kernel(
    const bf16_t* __restrict__ Ah, const bf16_t* __restrict__ Al,
    const bf16_t* __restrict__ Bth, const bf16_t* __restrict__ Btl,
    float* __restrict__ C, int M, int N, int K)
{
  __shared__ bf16_t Ash[128][72];
  __shared__ bf16_t Asl[128][72];
  __shared__ bf16_t Bsh[64][72];
  __shared__ bf16_t Bsl[64][72];
  const int tid = threadIdx.x;
  const int m0 = blockIdx.x * 128, n0 = blockIdx.y * 64;
  const int w = tid >> 6, lane = tid & 63;
  const int wr = w >> 1, wc = w & 1;
  const int ln = lane & 15, qd = lane >> 4;
  f32x4 zero = {0.f, 0.f, 0.f, 0.f};
  f32x4 acc[4][2];
#pragma unroll
  for (int a = 0; a < 4; a++)
#pragma unroll
    for (int b = 0; b < 2; b++) acc[a][b] = zero;

  for (int k0 = 0; k0 < K; k0 += 64) {
    __syncthreads();
#pragma unroll
    for (int i = 0; i < 4; i++) {
      int vid = tid + i*256;
      int r = vid >> 3, c8 = (vid & 7) * 8;
      *(bf16x8*)&Ash[r][c8] = *(const bf16x8*)(Ah + (size_t)(m0+r)*K + k0 + c8);
      *(bf16x8*)&Asl[r][c8] = *(const bf16x8*)(Al + (size_t)(m0+r)*K + k0 + c8);
    }
#pragma unroll
    for (int i = 0; i < 2; i++) {
      int vid = tid + i*256;
      int r = vid >> 3, c8 = (vid & 7) * 8;
      *(bf16x8*)&Bsh[r][c8] = *(const bf16x8*)(Bth + (size_t)(n0+r)*K + k0 + c8);
      *(bf16x8*)&Bsl[r][c8] = *(const bf16x8*)(Btl + (size_t)(n0+r)*K + k0 + c8);
    }
    __syncthreads();
#pragma unroll
    for (int c = 0; c < 2; c++) {
      bf16x8 afh[4], afl[4], bfh[2], bfl[2];
#pragma unroll
      for (int mt = 0; mt < 4; mt++) {
        afh[mt] = *(const bf16x8*)&Ash[wr*64 + mt*16 + ln][c*32 + qd*8];
        afl[mt] = *(const bf16x8*)&Asl[wr*64 + mt*16 + ln][c*32 + qd*8];
      }
#pragma unroll
      for (int nt = 0; nt < 2; nt++) {
        bfh[nt] = *(const bf16x8*)&Bsh[wc*32 + nt*16 + ln][c*32 + qd*8];
        bfl[nt] = *(const bf16x8*)&Bsl[wc*32 + nt*16 + ln][c*32 + qd*8];
      }
#pragma unroll
      for (int mt = 0; mt < 4; mt++)
#pragma unroll
        for (int nt = 0; nt < 2; nt++) {
          acc[mt][nt] = __builtin_amdgcn_mfma_f32_16x16x32_bf16(afh[mt], bfl[nt], acc[mt][nt], 0, 0, 0);
          acc[mt][nt] = __builtin_amdgcn_mfma_f32_16x16x32_bf16(afl[mt], bfh[nt], acc[mt][nt], 0, 0, 0);
          acc[mt][nt] = __builtin_amdgcn_mfma_f32_16x16x32_bf16(afh[mt], bfh[nt], acc[mt][nt], 0, 0, 0);
        }
    }
  }
#pragma unroll
  for (int mt = 0; mt < 4; mt++)
#pragma unroll
    for (int nt = 0; nt < 2; nt++)
#pragma unroll
      for (int r = 0; r < 4; r++) {
        int gm = m0 + wr*64 + mt*16 + qd*4 + r;
        int gn = n0 + wc*32 + nt*16 + ln;
        C[(size_t)gm*N + gn] = acc[mt][nt][r];
      }
}

// =========================== GEGLU ===========================
__global__ __launch_bounds__(256) void geglu_kernel(
    const bf16_t* __restrict__ proj, bf16_t* __restrict__ gg)
{
  int idx = blockIdx.x * 256 + threadIdx.x;
  int m = idx / 320, c4 = (idx - m*320) * 4;
  bf16x4 a = *(const bf16x4*)(proj + (size_t)m*2560 + c4);
  bf16x4 g = *(const bf16x4*)(proj + (size_t)m*2560 + 1280 + c4);
  bf16x4 r;
#pragma unroll
  for (int i = 0; i < 4; i++) {
    float gf = b2f(g[i]);
    float ge = 0.5f * gf * (1.f + erff(gf * 0.70710678118654752f));
    r[i] = f2b(b2f(a[i]) * ge);
  }
  *(bf16x4*)(gg + (size_t)m*1280 + c4) = r;
}

// =========================== launch ===========================
extern "C" void kernel_launch(void* const* d_in, const int* in_sizes, int n_in,
                              void* d_out, int out_size, void* d_ws, size_t ws_size,
                              hipStream_t stream)
{
  const float* x    = (const float*)d_in[0];
  const float* ctx  = (const float*)d_in[1];
  const float* fam  = (const float*)d_in[2];
  const float* g1   = (const float*)d_in[3];
  const float* b1   = (const float*)d_in[4];
  const float* g2   = (const float*)d_in[5];
  const float* b2   = (const float*)d_in[6];
  const float* g3   = (const float*)d_in[7];
  const float* b3   = (const float*)d_in[8];
  const float* Wq1  = (const float*)d_in[9];
  const float* Wk1  = (const float*)d_in[10];
  const float* Wv1  = (const float*)d_in[11];
  const float* Wo1  = (const float*)d_in[12];
  const float* bo1  = (const float*)d_in[13];
  const float* Wq2  = (const float*)d_in[14];
  const float* Wk2  = (const float*)d_in[15];
  const float* Wv2  = (const float*)d_in[16];
  const float* Wo2  = (const float*)d_in[17];
  const float* bo2  = (const float*)d_in[18];
  const float* Wff1 = (const float*)d_in[19];
  const float* bff1 = (const float*)d_in[20];
  const float* Wff2 = (const float*)d_in[21];
  const float* bff2 = (const float*)d_in[22];
  const int*   ufca = (const int*)d_in[23];

  char* ws = (char*)d_ws;
  bf16_t* qkvb = (bf16_t*)(ws + 0);          //  7,864,320  bf16 [4096][960] (Q pre-scaled)
  f16_t*  vtg  = (f16_t*)(ws + 7864320);     //  3,145,728  f16 [8][48][4096] (row40=1)
  bf16_t* o1a  = (bf16_t*)(ws + 11010048);   //  2,621,440  bf16 [4096][320]
  bf16_t* h1b  = (bf16_t*)(ws + 13631488);   //  2,621,440
  bf16_t* h2hi = (bf16_t*)(ws + 16252928);   //  2,621,440
  bf16_t* h2lo = (bf16_t*)(ws + 18874368);   //  2,621,440
  float*  x2   = (float*)(ws + 21495808);    //  5,242,880
  float*  q2   = (float*)(ws + 26738688);    //  5,242,880
  float*  kv2  = (float*)(ws + 31981568);    //    197,120
  bf16_t* o2   = (bf16_t*)(ws + 32178688);   //  2,621,440
  float*  x3   = (float*)(ws + 34800128);    //  5,242,880
  bf16_t* h3b  = (bf16_t*)(ws + 40043008);   //  2,621,440
  bf16_t* wqkvt = (bf16_t*)(ws + 42664448);  //    614,400
  bf16_t* wo1t  = (bf16_t*)(ws + 43278848);  //    204,800
  float*  wkv2t = (float*)(ws + 43483648);   //  1,966,080
  bf16_t* wo2t  = (bf16_t*)(ws + 45449728);  //    204,800
  bf16_t* wff1t = (bf16_t*)(ws + 45654528);  //  1,638,400
  bf16_t* wff2t = (bf16_t*)(ws + 47292928);  //    819,200
  float*  lpart = (float*)(ws + 48112128);   //    524,288  f32 [4][8][4096]
  bf16_t* wq2th = (bf16_t*)(ws + 48636416);  //    204,800
  bf16_t* wq2tl = (bf16_t*)(ws + 48841216);  //    204,800
  bf16_t* famh  = (bf16_t*)(ws + 49046016);  //     18,432
  bf16_t* faml  = (bf16_t*)(ws + 49064448);  //     18,432
  bf16_t* k2h   = (bf16_t*)(ws + 49082880);  //     98,304
  bf16_t* k2l   = (bf16_t*)(ws + 49181184);  //     98,304
  bf16_t* v2t   = (bf16_t*)(ws + 49279488);  //     73,728  -> end 49,353,216
  // opart (bf16, 4 splits) overlays x2+q2 (dead during flash+merge):
  // [4][8][4096][40] bf16 = 10,485,760 B at 21,495,808 .. 31,981,568
  bf16_t* opart = (bf16_t*)(ws + 21495808);
  bf16_t* proj = (bf16_t*)(ws + 0);          // bf16 [4096][2560] (FF phase; overlays qkvb..h2lo)
  bf16_t* gg   = (bf16_t*)(ws + 21495808);   // bf16 [4096][1280] (FF phase; overlays x2,q2)

  float* xout = (float*)d_out;

  prep_kernel<<<1024, 256, 0, stream>>>(Wq1, Wk1, Wv1, Wo1, Wq2, Wk2, Wv2, Wo2, Wff1, Wff2, fam,
                                        wqkvt, wo1t, wkv2t, wo2t, wff1t, wff2t, wq2th, wq2tl,
                                        famh, faml);
  // --- attn1 (bf16/f16 MFMA flash) ---
  ln_kernel<bf16_t><<<1024, 256, 0, stream>>>(x, g1, b1, h1b);
  gemm_bf16_kernel<1><<<dim3(32,15), 256, 0, stream>>>(h1b, wqkvt, nullptr, nullptr, qkvb, 4096, 960, 320);
  repack_vt_kernel<<<dim3(64,8), 256, 0, stream>>>(qkvb, vtg);
  flash_self_kernel<<<dim3(64,8,4), 256, 0, stream>>>(qkvb, vtg, opart, lpart);
  merge_o1_kernel<<<5120, 256, 0, stream>>>(opart, lpart, o1a);
  gemm_bf16_64_kernel<0><<<dim3(64,5), 256, 0, stream>>>(o1a, wo1t, bo1, x, x2, 4096, 320, 320);
  // --- attn2 (sim2 path: fp32-emulated MFMA throughout) ---
  ln2_split_kernel<<<1024, 256, 0, stream>>>(x2, g2, b2, h2hi, h2lo);
  gemm3_kernel<<<dim3(32,5), 256, 0, stream>>>(h2hi, h2lo, wq2th, wq2tl, q2, 4096, 320, 320);
  kv2_dot_kernel<<<3080, 256, 0, stream>>>(ctx, wkv2t, kv2);
  kv2_post_kernel<<<336, 256, 0, stream>>>(kv2, k2h, k2l, v2t);
  attn_cross_kernel<<<dim3(64,8), 256, 0, stream>>>(q2, k2h, k2l, famh, faml, v2t, ufca, o2);
  gemm_bf16_64_kernel<0><<<dim3(64,5), 256, 0, stream>>>(o2, wo2t, bo2, x2, x3, 4096, 320, 320);
  // --- GEGLU FF ---
  ln_kernel<bf16_t><<<1024, 256, 0, stream>>>(x3, g3, b3, h3b);
  gemm_bf16_kernel<1><<<dim3(32,40), 256, 0, stream>>>(h3b, wff1t, bff1, nullptr, proj, 4096, 2560, 320);
  geglu_kernel<<<5120, 256, 0, stream>>>(proj, gg);
  gemm_bf16_64_kernel<0><<<dim3(64,5), 256, 0, stream>>>(gg, wff2t, bff2, x3, xout, 4096, 320, 1280);
}

// Round 10
// 344.223 us; speedup vs baseline: 1.1564x; 1.1564x over previous
//
#include <hip/hip_runtime.h>
#include <math.h>

typedef __bf16 bf16_t;
typedef __bf16 bf16x8 __attribute__((ext_vector_type(8)));
typedef __bf16 bf16x4 __attribute__((ext_vector_type(4)));
typedef float  f32x4  __attribute__((ext_vector_type(4)));
typedef _Float16 f16_t;
typedef _Float16 f16x4 __attribute__((ext_vector_type(4)));
typedef __fp16 hf16x2 __attribute__((ext_vector_type(2)));

static constexpr float ATT_SCALE = 0.15811388300841897f; // 40^-0.5
static constexpr float SC2 = 0.22811031f;                // ATT_SCALE * log2(e)
static constexpr float LOG2E = 1.4426950408889634f;

__device__ __forceinline__ bf16_t f2b(float f) {
  unsigned u = __float_as_uint(f);
  u = (u + 0x7fffu + ((u >> 16) & 1u)) >> 16;   // RNE
  unsigned short s = (unsigned short)u;
  bf16_t r;
  *(unsigned short*)&r = s;
  return r;
}
__device__ __forceinline__ float b2f(bf16_t b) {
  unsigned short s = *(const unsigned short*)&b;
  return __uint_as_float(((unsigned)s) << 16);
}
__device__ __forceinline__ void sto(float v, float* p)  { *p = v; }
__device__ __forceinline__ void sto(float v, bf16_t* p) { *p = f2b(v); }
__device__ __forceinline__ unsigned pkh2(float a, float b) {
  hf16x2 h = __builtin_amdgcn_cvt_pkrtz(a, b);
  return *(unsigned*)&h;
}

// =========================== weight repack ===========================
__global__ __launch_bounds__(256) void prep_kernel(
    const float* __restrict__ Wq1, const float* __restrict__ Wk1, const float* __restrict__ Wv1,
    const float* __restrict__ Wo1, const float* __restrict__ Wq2,
    const float* __restrict__ Wk2, const float* __restrict__ Wv2, const float* __restrict__ Wo2,
    const float* __restrict__ Wff1, const float* __restrict__ Wff2,
    const float* __restrict__ fam,
    bf16_t* __restrict__ wqkvt, bf16_t* __restrict__ wo1t, float* __restrict__ wkv2t,
    bf16_t* __restrict__ wo2t, bf16_t* __restrict__ wff1t, bf16_t* __restrict__ wff2t,
    bf16_t* __restrict__ wq2th, bf16_t* __restrict__ wq2tl,
    bf16_t* __restrict__ famh, bf16_t* __restrict__ faml)
{
  const int T1 = 960*320;
  const int T2 = T1 + 320*320;
  const int T3 = T2 + 768*640;
  const int T4 = T3 + 320*320;
  const int T5 = T4 + 2560*320;
  const int T6 = T5 + 320*1280;
  const int T7 = T6 + 320*320;
  const int T8 = T7 + 96*96;
  for (int i = blockIdx.x*256 + threadIdx.x; i < T8; i += gridDim.x*256) {
    if (i < T1) {
      int n = i / 320, k = i - n*320;
      float v = (n < 320) ? Wq1[k*320+n] * SC2
              : (n < 640) ? Wk1[k*320+n-320] : Wv1[k*320+n-640];
      wqkvt[i] = f2b(v);
    } else if (i < T2) {
      int e = i - T1; int n = e / 320, k = e - n*320;
      wo1t[e] = f2b(Wo1[k*320+n]);
    } else if (i < T3) {
      int e = i - T2; int n = e / 768, k = e - n*768;
      wkv2t[e] = (n < 320) ? Wk2[k*320+n] : Wv2[k*320+n-320];
    } else if (i < T4) {
      int e = i - T3; int n = e / 320, k = e - n*320;
      wo2t[e] = f2b(Wo2[k*320+n]);
    } else if (i < T5) {
      int e = i - T4; int n = e / 320, k = e - n*320;
      wff1t[e] = f2b(Wff1[(size_t)k*2560+n]);
    } else if (i < T6) {
      int e = i - T5; int n = e / 1280, k = e - n*1280;
      wff2t[e] = f2b(Wff2[k*320+n]);
    } else if (i < T7) {
      int e = i - T6; int n = e / 320, k = e - n*320;
      float v = Wq2[k*320+n];
      bf16_t h = f2b(v);
      wq2th[e] = h;
      wq2tl[e] = f2b(v - b2f(h));
    } else {
      int e = i - T7; int d = e / 96, k = e - d*96;
      float v = (d < 77 && k < 77) ? fam[d*77 + k] : 0.f;
      bf16_t h = f2b(v);
      famh[e] = h;
      faml[e] = f2b(v - b2f(h));
    }
  }
}

// =========================== LayerNorm ===========================
template<typename OT>
__global__ __launch_bounds__(256) void ln_kernel(
    const float* __restrict__ x, const float* __restrict__ g, const float* __restrict__ b,
    OT* __restrict__ out)
{
  const int lane = threadIdx.x & 63;
  const int row = blockIdx.x * 4 + (threadIdx.x >> 6);
  const float* xr = x + (size_t)row * 320;
  float v[5], s = 0.f, s2 = 0.f;
#pragma unroll
  for (int i = 0; i < 5; i++) { v[i] = xr[lane + i*64]; s += v[i]; s2 += v[i]*v[i]; }
#pragma unroll
  for (int o = 32; o; o >>= 1) { s += __shfl_xor(s, o); s2 += __shfl_xor(s2, o); }
  float mu = s * (1.f/320.f);
  float rs = rsqrtf(fmaxf(s2*(1.f/320.f) - mu*mu, 0.f) + 1e-5f);
#pragma unroll
  for (int i = 0; i < 5; i++) {
    int c = lane + i*64;
    sto((v[i]-mu)*rs*g[c] + b[c], &out[(size_t)row*320 + c]);
  }
}

// LayerNorm writing hi/lo bf16 split
__global__ __launch_bounds__(256) void ln2_split_kernel(
    const float* __restrict__ x, const float* __restrict__ g, const float* __restrict__ b,
    bf16_t* __restrict__ hi, bf16_t* __restrict__ lo)
{
  const int lane = threadIdx.x & 63;
  const int row = blockIdx.x * 4 + (threadIdx.x >> 6);
  const float* xr = x + (size_t)row * 320;
  float v[5], s = 0.f, s2 = 0.f;
#pragma unroll
  for (int i = 0; i < 5; i++) { v[i] = xr[lane + i*64]; s += v[i]; s2 += v[i]*v[i]; }
#pragma unroll
  for (int o = 32; o; o >>= 1) { s += __shfl_xor(s, o); s2 += __shfl_xor(s2, o); }
  float mu = s * (1.f/320.f);
  float rs = rsqrtf(fmaxf(s2*(1.f/320.f) - mu*mu, 0.f) + 1e-5f);
#pragma unroll
  for (int i = 0; i < 5; i++) {
    int c = lane + i*64;
    float y = (v[i]-mu)*rs*g[c] + b[c];
    bf16_t h = f2b(y);
    hi[(size_t)row*320 + c] = h;
    lo[(size_t)row*320 + c] = f2b(y - b2f(h));
  }
}

// =========================== kv2 dot-product GEMM ===========================
__global__ __launch_bounds__(256) void kv2_dot_kernel(
    const float* __restrict__ ctx, const float* __restrict__ wkv2t, float* __restrict__ kv2)
{
  const int gid = blockIdx.x*16 + (threadIdx.x >> 4);
  const int q = threadIdx.x & 15;
  const int m = gid / 640, n = gid - m*640;
  const float4* a = (const float4*)(ctx + (size_t)m*768);
  const float4* b = (const float4*)(wkv2t + (size_t)n*768);
  float acc = 0.f;
#pragma unroll
  for (int i = 0; i < 12; i++) {
    float4 av = a[i*16+q], bv = b[i*16+q];
    acc += av.x*bv.x + av.y*bv.y + av.z*bv.z + av.w*bv.w;
  }
#pragma unroll
  for (int o = 8; o; o >>= 1) acc += __shfl_xor(acc, o);
  if (q == 0) kv2[(size_t)m*640 + n] = acc;
}

// =========================== kv2 post: K2 hi/lo and V^T ===========================
__global__ __launch_bounds__(256) void kv2_post_kernel(
    const float* __restrict__ kv2, bf16_t* __restrict__ k2h, bf16_t* __restrict__ k2l,
    bf16_t* __restrict__ v2t)
{
  const int NK = 8*96*64;
  const int NV = 8*48*96;
  int i = blockIdx.x*256 + threadIdx.x;
  if (i < NK) {
    int h = i / (96*64), r = i - h*96*64, j = r >> 6, d = r & 63;
    float v = (j < 77 && d < 40) ? kv2[(size_t)j*640 + h*40 + d] : 0.f;
    bf16_t hh = f2b(v);
    k2h[i] = hh;
    k2l[i] = f2b(v - b2f(hh));
  } else if (i < NK + NV) {
    int e = i - NK;
    int h = e / (48*96), r = e - h*48*96, d = r / 96, j = r - d*96;
    v2t[e] = f2b((d < 40 && j < 77) ? kv2[(size_t)j*640 + 320 + h*40 + d] : 0.f);
  }
}

// =========================== V^T repack (self-attn): f16, 48 rows, row 40 = ones ===========================
__global__ __launch_bounds__(256) void repack_vt_kernel(
    const bf16_t* __restrict__ qkvb, f16_t* __restrict__ vtg)
{
  __shared__ f16_t T[64*44];
  const int tid = threadIdx.x;
  const int t0 = blockIdx.x * 64, h = blockIdx.y;
  for (int e = tid; e < 320; e += 256) {
    int t = e / 5, c8 = (e - t*5) * 8;
    bf16x8 v = *(const bf16x8*)(qkvb + (size_t)(t0+t)*960 + 640 + h*40 + c8);
    f16_t* dst = &T[t*44 + c8];
#pragma unroll
    for (int j = 0; j < 8; j++) dst[j] = (f16_t)b2f(v[j]);
  }
  __syncthreads();
  for (int e = tid; e < 320; e += 256) {
    int d = e >> 3, t8 = (e & 7) * 8;
    f16_t* dst = vtg + ((size_t)h*48 + d)*4096 + t0 + t8;
#pragma unroll
    for (int j = 0; j < 8; j++) dst[j] = T[(t8+j)*44 + d];
  }
  for (int e = tid; e < 512; e += 256) {
    int r = 40 + (e >> 6), t = e & 63;
    vtg[((size_t)h*48 + r)*4096 + t0 + t] = (r == 40) ? (f16_t)1.0f : (f16_t)0.0f;
  }
}

// =========================== bf16/f16 MFMA flash self-attention (v4 = R8 proven) ===========================
// block = 64 q-rows x 1 head; 4 waves own disjoint 16-key slices of each 64-key tile.
// K prefetch; p in f16; denominator via V^T ones-row; f32 opart (vector stores). grid (64, 8, 2).
__global__ __launch_bounds__(256, 4) void flash_self_kernel(
    const bf16_t* __restrict__ qkvb, const f16_t* __restrict__ vtg,
    float* __restrict__ opart, float* __restrict__ lpart)
{
  __shared__ float Red[6144];      // 24 KB, two-pass epilogue
  const int tid = threadIdx.x;
  const int w = tid >> 6, lane = tid & 63;
  const int ln = lane & 15, qd = lane >> 4;
  const int h = blockIdx.y;
  const int q0 = blockIdx.x * 64;
  const int split = blockIdx.z;

  bf16x8 zero8 = {};
  bf16x8 bq[4][2];
#pragma unroll
  for (int nt = 0; nt < 4; nt++) {
    const bf16_t* qp = qkvb + (size_t)(q0 + nt*16 + ln)*960 + h*40;
    bq[nt][0] = *(const bf16x8*)(qp + qd*8);
    bq[nt][1] = (qd == 0) ? *(const bf16x8*)(qp + 32) : zero8;
  }

  f32x4 zero4 = {0.f,0.f,0.f,0.f};
  f32x4 oacc[3][4];
#pragma unroll
  for (int a = 0; a < 3; a++)
#pragma unroll
    for (int b = 0; b < 4; b++) oacc[a][b] = zero4;

  const bf16_t* kbase = qkvb + 320 + h*40 + (size_t)(w*16 + ln)*960;
  const f16_t*  vrow  = vtg + (size_t)h*48*4096 + (size_t)ln*4096 + w*16 + qd*4;

  const bf16_t* kp0 = kbase + (size_t)(split*2048)*960;
  bf16x8 ka0 = *(const bf16x8*)(kp0 + qd*8);
  bf16x8 ka1 = (qd == 0) ? *(const bf16x8*)(kp0 + 32) : zero8;

  for (int kt = 0; kt < 32; kt++) {
    int k0 = split*2048 + kt*64;
    bf16x8 nka0 = zero8, nka1 = zero8;
    if (kt < 31) {
      const bf16_t* kpn = kbase + (size_t)(k0 + 64)*960;
      nka0 = *(const bf16x8*)(kpn + qd*8);
      if (qd == 0) nka1 = *(const bf16x8*)(kpn + 32);
    }

    f16x4 pb[4];
#pragma unroll
    for (int nt = 0; nt < 4; nt++) {
      f32x4 s = __builtin_amdgcn_mfma_f32_16x16x32_bf16(ka0, bq[nt][0], zero4, 0, 0, 0);
      s = __builtin_amdgcn_mfma_f32_16x16x32_bf16(ka1, bq[nt][1], s, 0, 0, 0);
      uint2 u;
      u.x = pkh2(__builtin_amdgcn_exp2f(s[0]), __builtin_amdgcn_exp2f(s[1]));
      u.y = pkh2(__builtin_amdgcn_exp2f(s[2]), __builtin_amdgcn_exp2f(s[3]));
      pb[nt] = *(f16x4*)&u;
    }
#pragma unroll
    for (int dt = 0; dt < 3; dt++) {
      f16x4 va = *(const f16x4*)(vrow + (size_t)dt*16*4096 + k0);
#pragma unroll
      for (int nt = 0; nt < 4; nt++)
        oacc[dt][nt] = __builtin_amdgcn_mfma_f32_16x16x16f16(va, pb[nt], oacc[dt][nt], 0, 0, 0);
    }
    ka0 = nka0;
    ka1 = nka1;
  }

  // ---- epilogue: two-pass cross-wave (key-slice) reduction via LDS ----
  float* obase = opart + ((size_t)(split*8 + h)*4096 + q0)*40;
  for (int np = 0; np < 2; np++) {
    __syncthreads();
#pragma unroll
    for (int e = 0; e < 2; e++) {
      int nt = np*2 + e;
#pragma unroll
      for (int dt = 0; dt < 3; dt++)
        *(f32x4*)&Red[((w*2 + e)*3 + dt)*256 + ln*16 + qd*4] = oacc[dt][nt];
    }
    __syncthreads();
    int e = tid >> 7;
    int lq = (tid >> 3) & 15;
    int dbase = tid & 7;
#pragma unroll
    for (int i = 0; i < 5; i++) {
      int d = dbase + i*8;
      int dt = d >> 4, drow = d & 15;
      float v = Red[((0*2+e)*3 + dt)*256 + lq*16 + drow]
              + Red[((1*2+e)*3 + dt)*256 + lq*16 + drow]
              + Red[((2*2+e)*3 + dt)*256 + lq*16 + drow]
              + Red[((3*2+e)*3 + dt)*256 + lq*16 + drow];
      obase[(size_t)((np*2+e)*16 + lq)*40 + d] = v;
    }
    if (dbase == 0) {
      float l = Red[((0*2+e)*3 + 2)*256 + lq*16 + 8]
              + Red[((1*2+e)*3 + 2)*256 + lq*16 + 8]
              + Red[((2*2+e)*3 + 2)*256 + lq*16 + 8]
              + Red[((3*2+e)*3 + 2)*256 + lq*16 + 8];
      lpart[(size_t)(split*8 + h)*4096 + q0 + (np*2+e)*16 + lq] = l;
    }
  }
}

// =========================== merge K-split partials (2 splits, f32 opart) ===========================
__global__ __launch_bounds__(256) void merge_o1_kernel(
    const float* __restrict__ op, const float* __restrict__ lp, bf16_t* __restrict__ o1a)
{
  int i = blockIdx.x*256 + threadIdx.x;
  int q = i / 320, c = i - q*320;
  int h = c / 40, d = c - h*40;
  size_t base = ((size_t)h*4096 + q)*40 + d;
  float l = lp[h*4096 + q] + lp[32768 + h*4096 + q];
  float o = op[base] + op[base + 1310720];
  o1a[i] = f2b(o / l);
}

// =========================== cross-attention (all-MFMA, single-pass, no barriers) ===========================
__global__ __launch_bounds__(256) void attn_cross_kernel(
    const float* __restrict__ q2, const bf16_t* __restrict__ k2h, const bf16_t* __restrict__ k2l,
    const bf16_t* __restrict__ famh, const bf16_t* __restrict__ faml,
    const bf16_t* __restrict__ v2t, const int* __restrict__ use_fca,
    bf16_t* __restrict__ o2)
{
  __shared__ bf16_t SMh[4][16*96];
  __shared__ bf16_t SMl[4][16*96];
  __shared__ bf16_t PAs[4][16*96];
  const int tid = threadIdx.x;
  const int w = tid >> 6, lane = tid & 63;
  const int ln = lane & 15, qd = lane >> 4;
  const int h = blockIdx.y;
  const int q0 = blockIdx.x*64 + w*16;
  const int fca = use_fca[0];
  bf16_t* smh = SMh[w];
  bf16_t* sml = SMl[w];
  bf16_t* pa  = PAs[w];

  {
    bf16x4 z = {};
    int q = lane >> 2, c = 80 + (lane & 3)*4;
    *(bf16x4*)&smh[q*96 + c] = z;
    *(bf16x4*)&sml[q*96 + c] = z;
    *(bf16x4*)&pa [q*96 + c] = z;
  }

  bf16x8 zero8 = {};
  bf16x8 aqh0, aql0, aqh1 = zero8, aql1 = zero8;
  {
    const float* qp = q2 + (size_t)(q0 + ln)*320 + h*40;
    float4 v0 = *(const float4*)(qp + qd*8);
    float4 v1 = *(const float4*)(qp + qd*8 + 4);
    float qv[8] = {v0.x,v0.y,v0.z,v0.w,v1.x,v1.y,v1.z,v1.w};
#pragma unroll
    for (int i = 0; i < 8; i++) {
      bf16_t hh = f2b(qv[i]);
      aqh0[i] = hh; aql0[i] = f2b(qv[i] - b2f(hh));
    }
    if (qd == 0) {
      float4 u0 = *(const float4*)(qp + 32);
      float4 u1 = *(const float4*)(qp + 36);
      float uv[8] = {u0.x,u0.y,u0.z,u0.w,u1.x,u1.y,u1.z,u1.w};
#pragma unroll
      for (int i = 0; i < 8; i++) {
        bf16_t hh = f2b(uv[i]);
        aqh1[i] = hh; aql1[i] = f2b(uv[i] - b2f(hh));
      }
    }
  }

  f32x4 zero4 = {0.f,0.f,0.f,0.f};
  float ss[5][4];
#pragma unroll
  for (int nt = 0; nt < 5; nt++) {
    const bf16_t* kb = k2h + ((size_t)h*96 + nt*16 + ln)*64 + qd*8;
    const bf16_t* kl = k2l + ((size_t)h*96 + nt*16 + ln)*64 + qd*8;
    bf16x8 kh0 = *(const bf16x8*)kb;
    bf16x8 kh1 = *(const bf16x8*)(kb + 32);
    bf16x8 kl0 = *(const bf16x8*)kl;
    bf16x8 kl1 = *(const bf16x8*)(kl + 32);
    f32x4 s;
    s = __builtin_amdgcn_mfma_f32_16x16x32_bf16(aqh0, kl0, zero4, 0, 0, 0);
    s = __builtin_amdgcn_mfma_f32_16x16x32_bf16(aql0, kh0, s, 0, 0, 0);
    s = __builtin_amdgcn_mfma_f32_16x16x32_bf16(aqh0, kh0, s, 0, 0, 0);
    s = __builtin_amdgcn_mfma_f32_16x16x32_bf16(aqh1, kl1, s, 0, 0, 0);
    s = __builtin_amdgcn_mfma_f32_16x16x32_bf16(aql1, kh1, s, 0, 0, 0);
    s = __builtin_amdgcn_mfma_f32_16x16x32_bf16(aqh1, kh1, s, 0, 0, 0);
#pragma unroll
    for (int r = 0; r < 4; r++) {
      float sv = s[r] * ATT_SCALE;
      ss[nt][r] = sv;
      bf16_t hh = f2b(sv);
      smh[(qd*4 + r)*96 + nt*16 + ln] = hh;
      sml[(qd*4 + r)*96 + nt*16 + ln] = f2b(sv - b2f(hh));
    }
  }

  f32x4 facc[5];
#pragma unroll
  for (int nt = 0; nt < 5; nt++) facc[nt] = zero4;
#pragma unroll
  for (int c = 0; c < 3; c++) {
    bf16x8 sah = *(const bf16x8*)&smh[ln*96 + c*32 + qd*8];
    bf16x8 sal = *(const bf16x8*)&sml[ln*96 + c*32 + qd*8];
#pragma unroll
    for (int nt = 0; nt < 5; nt++) {
      bf16x8 fh8 = *(const bf16x8*)(famh + ((size_t)(nt*16 + ln))*96 + c*32 + qd*8);
      bf16x8 fl8 = *(const bf16x8*)(faml + ((size_t)(nt*16 + ln))*96 + c*32 + qd*8);
      facc[nt] = __builtin_amdgcn_mfma_f32_16x16x32_bf16(sah, fl8, facc[nt], 0, 0, 0);
      facc[nt] = __builtin_amdgcn_mfma_f32_16x16x32_bf16(sal, fh8, facc[nt], 0, 0, 0);
      facc[nt] = __builtin_amdgcn_mfma_f32_16x16x32_bf16(sah, fh8, facc[nt], 0, 0, 0);
    }
  }

  float pr[5][4];
  if (fca) {
    float fwv[5][4], fm[4];
#pragma unroll
    for (int nt = 0; nt < 5; nt++)
#pragma unroll
      for (int r = 0; r < 4; r++) fwv[nt][r] = fminf(fabsf(facc[nt][r]), 1.f);
#pragma unroll
    for (int r = 0; r < 4; r++) {
      float m = fmaxf(fmaxf(fwv[0][r], fwv[1][r]), fmaxf(fwv[2][r], fmaxf(fwv[3][r], fwv[4][r])));
#pragma unroll
      for (int o = 8; o; o >>= 1) m = fmaxf(m, __shfl_xor(m, o));
      fm[r] = m;
    }
#pragma unroll
    for (int nt = 0; nt < 5; nt++)
#pragma unroll
      for (int r = 0; r < 4; r++) {
        float lg = ss[nt][r] - ((fwv[nt][r] > 0.6f*(fm[r] + 1e-6f)) ? 0.f : 50.f);
        pr[nt][r] = __builtin_amdgcn_exp2f(lg * LOG2E);
      }
  } else {
#pragma unroll
    for (int nt = 0; nt < 5; nt++)
#pragma unroll
      for (int r = 0; r < 4; r++)
        pr[nt][r] = __builtin_amdgcn_exp2f(ss[nt][r] * LOG2E);
  }
  if (ln >= 13) {
#pragma unroll
    for (int r = 0; r < 4; r++) pr[4][r] = 0.f;
  }
  float l_[4] = {0.f,0.f,0.f,0.f};
#pragma unroll
  for (int nt = 0; nt < 5; nt++)
#pragma unroll
    for (int r = 0; r < 4; r++) {
      l_[r] += pr[nt][r];
      pa[(qd*4 + r)*96 + nt*16 + ln] = f2b(pr[nt][r]);
    }
#pragma unroll
  for (int r = 0; r < 4; r++)
#pragma unroll
    for (int o = 8; o; o >>= 1) l_[r] += __shfl_xor(l_[r], o);

  f32x4 oacc[3];
#pragma unroll
  for (int nt = 0; nt < 3; nt++) oacc[nt] = zero4;
#pragma unroll
  for (int c = 0; c < 3; c++) {
    bf16x8 paf = *(const bf16x8*)&pa[ln*96 + c*32 + qd*8];
#pragma unroll
    for (int nt = 0; nt < 3; nt++) {
      bf16x8 vb = *(const bf16x8*)(v2t + ((size_t)h*48 + nt*16 + ln)*96 + c*32 + qd*8);
      oacc[nt] = __builtin_amdgcn_mfma_f32_16x16x32_bf16(paf, vb, oacc[nt], 0, 0, 0);
    }
  }
  float inv[4];
#pragma unroll
  for (int r = 0; r < 4; r++) inv[r] = 1.f / l_[r];
#pragma unroll
  for (int nt = 0; nt < 3; nt++) {
    int d = nt*16 + ln;
    if (d < 40) {
#pragma unroll
      for (int r = 0; r < 4; r++)
        o2[(size_t)(q0 + qd*4 + r)*320 + h*40 + d] = f2b(oacc[nt][r]*inv[r]);
    }
  }
}

// =========================== bf16 MFMA GEMM 128x64 ===========================
template<int OUT_BF16>
__global__ __launch_bounds__(256) void gemm_bf16_kernel(
    const bf16_t* __restrict__ A, const bf16_t* __restrict__ Bt,
    const float* __restrict__ bias, const float* __restrict__ resid,
    void* __restrict__ Cout, int M, int N, int K)
{
  __shared__ bf16_t As[128][72];
  __shared__ bf16_t Bs[64][72];
  const int tid = threadIdx.x;
  const int m0 = blockIdx.x * 128, n0 = blockIdx.y * 64;
  const int w = tid >> 6, lane = tid & 63;
  const int wr = w >> 1, wc = w & 1;
  const int ln = lane & 15, qd = lane >> 4;
  f32x4 zero = {0.f, 0.f, 0.f, 0.f};
  f32x4 acc[4][2];
#pragma unroll
  for (int a = 0; a < 4; a++)
#pragma unroll
    for (int b = 0; b < 2; b++) acc[a][b] = zero;

  for (int k0 = 0; k0 < K; k0 += 64) {
    __syncthreads();
#pragma unroll
    for (int i = 0; i < 4; i++) {
      int vid = tid + i*256;
      int r = vid >> 3, c8 = (vid & 7) * 8;
      *(bf16x8*)&As[r][c8] = *(const bf16x8*)(A + (size_t)(m0+r)*K + k0 + c8);
    }
#pragma unroll
    for (int i = 0; i < 2; i++) {
      int vid = tid + i*256;
      int r = vid >> 3, c8 = (vid & 7) * 8;
      *(bf16x8*)&Bs[r][c8] = *(const bf16x8*)(Bt + (size_t)(n0+r)*K + k0 + c8);
    }
    __syncthreads();
#pragma unroll
    for (int c = 0; c < 2; c++) {
      bf16x8 af[4], bfr[2];
#pragma unroll
      for (int mt = 0; mt < 4; mt++)
        af[mt] = *(const bf16x8*)&As[wr*64 + mt*16 + ln][c*32 + qd*8];
#pragma unroll
      for (int nt = 0; nt < 2; nt++)
        bfr[nt] = *(const bf16x8*)&Bs[wc*32 + nt*16 + ln][c*32 + qd*8];
#pragma unroll
      for (int mt = 0; mt < 4; mt++)
#pragma unroll
        for (int nt = 0; nt < 2; nt++)
          acc[mt][nt] = __builtin_amdgcn_mfma_f32_16x16x32_bf16(af[mt], bfr[nt], acc[mt][nt], 0, 0, 0);
    }
  }
#pragma unroll
  for (int mt = 0; mt < 4; mt++)
#pragma unroll
    for (int nt = 0; nt < 2; nt++)
#pragma unroll
      for (int r = 0; r < 4; r++) {
        int gm = m0 + wr*64 + mt*16 + qd*4 + r;
        int gn = n0 + wc*32 + nt*16 + ln;
        float v = acc[mt][nt][r];
        if (bias)  v += bias[gn];
        if (resid) v += resid[(size_t)gm*N + gn];
        if (OUT_BF16) sto(v, &((bf16_t*)Cout)[(size_t)gm*N + gn]);
        else          sto(v, &((float*)Cout)[(size_t)gm*N + gn]);
      }
}

// =========================== bf16 MFMA GEMM 64x64 (2x block count for narrow-N GEMMs) ===========================
template<int OUT_BF16>
__global__ __launch_bounds__(256) void gemm_bf16_64_kernel(
    const bf16_t* __restrict__ A, const bf16_t* __restrict__ Bt,
    const float* __restrict__ bias, const float* __restrict__ resid,
    void* __restrict__ Cout, int M, int N, int K)
{
  __shared__ bf16_t As[64][72];
  __shared__ bf16_t Bs[64][72];
  const int tid = threadIdx.x;
  const int m0 = blockIdx.x * 64, n0 = blockIdx.y * 64;
  const int w = tid >> 6, lane = tid & 63;
  const int wr = w >> 1, wc = w & 1;
  const int ln = lane & 15, qd = lane >> 4;
  f32x4 zero = {0.f, 0.f, 0.f, 0.f};
  f32x4 acc[2][2];
#pragma unroll
  for (int a = 0; a < 2; a++)
#pragma unroll
    for (int b = 0; b < 2; b++) acc[a][b] = zero;

  for (int k0 = 0; k0 < K; k0 += 64) {
    __syncthreads();
#pragma unroll
    for (int i = 0; i < 2; i++) {
      int vid = tid + i*256;
      int r = vid >> 3, c8 = (vid & 7) * 8;
      *(bf16x8*)&As[r][c8] = *(const bf16x8*)(A + (size_t)(m0+r)*K + k0 + c8);
      *(bf16x8*)&Bs[r][c8] = *(const bf16x8*)(Bt + (size_t)(n0+r)*K + k0 + c8);
    }
    __syncthreads();
#pragma unroll
    for (int c = 0; c < 2; c++) {
      bf16x8 af[2], bfr[2];
#pragma unroll
      for (int mt = 0; mt < 2; mt++)
        af[mt] = *(const bf16x8*)&As[wr*32 + mt*16 + ln][c*32 + qd*8];
#pragma unroll
      for (int nt = 0; nt < 2; nt++)
        bfr[nt] = *(const bf16x8*)&Bs[wc*32 + nt*16 + ln][c*32 + qd*8];
#pragma unroll
      for (int mt = 0; mt < 2; mt++)
#pragma unroll
        for (int nt = 0; nt < 2; nt++)
          acc[mt][nt] = __builtin_amdgcn_mfma_f32_16x16x32_bf16(af[mt], bfr[nt], acc[mt][nt], 0, 0, 0);
    }
  }
#pragma unroll
  for (int mt = 0; mt < 2; mt++)
#pragma unroll
    for (int nt = 0; nt < 2; nt++)
#pragma unroll
      for (int r = 0; r < 4; r++) {
        int gm = m0 + wr*32 + mt*16 + qd*4 + r;
        int gn = n0 + wc*32 + nt*16 + ln;
        float v = acc[mt][nt][r];
        if (bias)  v += bias[gn];
        if (resid) v += resid[(size_t)gm*N + gn];
        if (OUT_BF16) sto(v, &((bf16_t*)Cout)[(size_t)gm*N + gn]);
        else          sto(v, &((float*)Cout)[(size_t)gm*N + gn]);
      }
}

// =========================== 3-term bf16 MFMA GEMM (fp32 emulation), 64x64 tile ===========================
__global__ __launch_bounds__(256) void gemm3_64_kernel(
    const bf16_t* __restrict__ Ah, const bf16_t* __restrict__ Al,
    const bf16_t* __restrict__ Bth, const bf16_t* __restrict__ Btl,
    float* __restrict__ C, int M, int N, int K)
{
  __shared__ bf16_t Ash[64][72];
  __shared__ bf16_t Asl[64][72];
  __shared__ bf16_t Bsh[64][72];
  __shared__ bf16_t Bsl[64][72];
  const int tid = threadIdx.x;
  const int m0 = blockIdx.x * 64, n0 = blockIdx.y * 64;
  const int w = tid >> 6, lane = tid & 63;
  const int wr = w >> 1, wc = w & 1;
  const int ln = lane & 15, qd = lane >> 4;
  f32x4 zero = {0.f, 0.f, 0.f, 0.f};
  f32x4 acc[2][2];
#pragma unroll
  for (int a = 0; a < 2; a++)
#pragma unroll
    for (int b = 0; b < 2; b++) acc[a][b] = zero;

  for (int k0 = 0; k0 < K; k0 += 64) {
    __syncthreads();
#pragma unroll
    for (int i = 0; i < 2; i++) {
      int vid = tid + i*256;
      int r = vid >> 3, c8 = (vid & 7) * 8;
      *(bf16x8*)&Ash[r][c8] = *(const bf16x8*)(Ah + (size_t)(m0+r)*K + k0 + c8);
      *(bf16x8*)&Asl[r][c8] = *(const bf16x8*)(Al + (size_t)(m0+r)*K + k0 + c8);
      *(bf16x8*)&Bsh[r][c8] = *(const bf16x8*)(Bth + (size_t)(n0+r)*K + k0 + c8);
      *(bf16x8*)&Bsl[r][c8] = *(const bf16x8*)(Btl + (size_t)(n0+r)*K + k0 + c8);
    }
    __syncthreads();
#pragma unroll
    for (int c = 0; c < 2; c++) {
      bf16x8 afh[2], afl[2], bfh[2], bfl[2];
#pragma unroll
      for (int mt = 0; mt < 2; mt++) {
        afh[mt] = *(const bf16x8*)&Ash[wr*32 + mt*16 + ln][c*32 + qd*8];
        afl[mt] = *(const bf16x8*)&Asl[wr*32 + mt*16 + ln][c*32 + qd*8];
      }
#pragma unroll
      for (int nt = 0; nt < 2; nt++) {
        bfh[nt] = *(const bf16x8*)&Bsh[wc*32 + nt*16 + ln][c*32 + qd*8];
        bfl[nt] = *(const bf16x8*)&Bsl[wc*32 + nt*16 + ln][c*32 + qd*8];
      }
#pragma unroll
      for (int mt = 0; mt < 2; mt++)
#pragma unroll
        for (int nt = 0; nt < 2; nt++) {
          acc[mt][nt] = __builtin_amdgcn_mfma_f32_16x16x32_bf16(afh[mt], bfl[nt], acc[mt][nt], 0, 0, 0);
          acc[mt][nt] = __builtin_amdgcn_mfma_f32_16x16x32_bf16(afl[mt], bfh[nt], acc[mt][nt], 0, 0, 0);
          acc[mt][nt] = __builtin_amdgcn_mfma_f32_16x16x32_bf16(afh[mt], bfh[nt], acc[mt][nt], 0, 0, 0);
        }
    }
  }
#pragma unroll
  for (int mt = 0; mt < 2; mt++)
#pragma unroll
    for (int nt = 0; nt < 2; nt++)
#pragma unroll
      for (int r = 0; r < 4; r++) {
        int gm = m0 + wr*32 + mt*16 + qd*4 + r;
        int gn = n0 + wc*32 + nt*16 + ln;
        C[(size_t)gm*N + gn] = acc[mt][nt][r];
      }
}

// =========================== GEGLU ===========================
__global__ __launch_bounds__(256) void geglu_kernel(
    const bf16_t* __restrict__ proj, bf16_t* __restrict__ gg)
{
  int idx = blockIdx.x * 256 + threadIdx.x;
  int m = idx / 320, c4 = (idx - m*320) * 4;
  bf16x4 a = *(const bf16x4*)(proj + (size_t)m*2560 + c4);
  bf16x4 g = *(const bf16x4*)(proj + (size_t)m*2560 + 1280 + c4);
  bf16x4 r;
#pragma unroll
  for (int i = 0; i < 4; i++) {
    float gf = b2f(g[i]);
    float ge = 0.5f * gf * (1.f + erff(gf * 0.70710678118654752f));
    r[i] = f2b(b2f(a[i]) * ge);
  }
  *(bf16x4*)(gg + (size_t)m*1280 + c4) = r;
}

// =========================== launch ===========================
extern "C" void kernel_launch(void* const* d_in, const int* in_sizes, int n_in,
                              void* d_out, int out_size, void* d_ws, size_t ws_size,
                              hipStream_t stream)
{
  const float* x    = (const float*)d_in[0];
  const float* ctx  = (const float*)d_in[1];
  const float* fam  = (const float*)d_in[2];
  const float* g1   = (const float*)d_in[3];
  const float* b1   = (const float*)d_in[4];
  const float* g2   = (const float*)d_in[5];
  const float* b2   = (const float*)d_in[6];
  const float* g3   = (const float*)d_in[7];
  const float* b3   = (const float*)d_in[8];
  const float* Wq1  = (const float*)d_in[9];
  const float* Wk1  = (const float*)d_in[10];
  const float* Wv1  = (const float*)d_in[11];
  const float* Wo1  = (const float*)d_in[12];
  const float* bo1  = (const float*)d_in[13];
  const float* Wq2  = (const float*)d_in[14];
  const float* Wk2  = (const float*)d_in[15];
  const float* Wv2  = (const float*)d_in[16];
  const float* Wo2  = (const float*)d_in[17];
  const float* bo2  = (const float*)d_in[18];
  const float* Wff1 = (const float*)d_in[19];
  const float* bff1 = (const float*)d_in[20];
  const float* Wff2 = (const float*)d_in[21];
  const float* bff2 = (const float*)d_in[22];
  const int*   ufca = (const int*)d_in[23];

  char* ws = (char*)d_ws;
  bf16_t* qkvb = (bf16_t*)(ws + 0);          //  7,864,320  bf16 [4096][960] (Q pre-scaled)
  f16_t*  vtg  = (f16_t*)(ws + 7864320);     //  3,145,728  f16 [8][48][4096] (row40=1)
  bf16_t* o1a  = (bf16_t*)(ws + 11010048);   //  2,621,440  bf16 [4096][320]
  bf16_t* h1b  = (bf16_t*)(ws + 13631488);   //  2,621,440
  bf16_t* h2hi = (bf16_t*)(ws + 16252928);   //  2,621,440
  bf16_t* h2lo = (bf16_t*)(ws + 18874368);   //  2,621,440
  float*  x2   = (float*)(ws + 21495808);    //  5,242,880
  float*  q2   = (float*)(ws + 26738688);    //  5,242,880
  float*  kv2  = (float*)(ws + 31981568);    //    197,120
  bf16_t* o2   = (bf16_t*)(ws + 32178688);   //  2,621,440
  float*  x3   = (float*)(ws + 34800128);    //  5,242,880
  bf16_t* h3b  = (bf16_t*)(ws + 40043008);   //  2,621,440
  bf16_t* wqkvt = (bf16_t*)(ws + 42664448);  //    614,400
  bf16_t* wo1t  = (bf16_t*)(ws + 43278848);  //    204,800
  float*  wkv2t = (float*)(ws + 43483648);   //  1,966,080
  bf16_t* wo2t  = (bf16_t*)(ws + 45449728);  //    204,800
  bf16_t* wff1t = (bf16_t*)(ws + 45654528);  //  1,638,400
  bf16_t* wff2t = (bf16_t*)(ws + 47292928);  //    819,200
  float*  lpart = (float*)(ws + 48112128);   //    262,144  f32 [2][8][4096]
  bf16_t* wq2th = (bf16_t*)(ws + 48374272);  //    204,800
  bf16_t* wq2tl = (bf16_t*)(ws + 48579072);  //    204,800
  bf16_t* famh  = (bf16_t*)(ws + 48783872);  //     18,432
  bf16_t* faml  = (bf16_t*)(ws + 48802304);  //     18,432
  bf16_t* k2h   = (bf16_t*)(ws + 48820736);  //     98,304
  bf16_t* k2l   = (bf16_t*)(ws + 48919040);  //     98,304
  bf16_t* v2t   = (bf16_t*)(ws + 49017344);  //     73,728  -> end 49,091,072
  // opart (f32, 2 splits) overlays x2+q2 (dead during flash+merge): [2][8][4096][40] f32 = 10,485,760
  float*  opart = (float*)(ws + 21495808);
  bf16_t* proj = (bf16_t*)(ws + 0);          // bf16 [4096][2560] (FF phase; overlays qkvb..h2lo)
  bf16_t* gg   = (bf16_t*)(ws + 21495808);   // bf16 [4096][1280] (FF phase; overlays x2,q2)

  float* xout = (float*)d_out;

  prep_kernel<<<2048, 256, 0, stream>>>(Wq1, Wk1, Wv1, Wo1, Wq2, Wk2, Wv2, Wo2, Wff1, Wff2, fam,
                                        wqkvt, wo1t, wkv2t, wo2t, wff1t, wff2t, wq2th, wq2tl,
                                        famh, faml);
  // --- attn1 (bf16/f16 MFMA flash) ---
  ln_kernel<bf16_t><<<1024, 256, 0, stream>>>(x, g1, b1, h1b);
  gemm_bf16_kernel<1><<<dim3(32,15), 256, 0, stream>>>(h1b, wqkvt, nullptr, nullptr, qkvb, 4096, 960, 320);
  repack_vt_kernel<<<dim3(64,8), 256, 0, stream>>>(qkvb, vtg);
  flash_self_kernel<<<dim3(64,8,2), 256, 0, stream>>>(qkvb, vtg, opart, lpart);
  merge_o1_kernel<<<5120, 256, 0, stream>>>(opart, lpart, o1a);
  gemm_bf16_64_kernel<0><<<dim3(64,5), 256, 0, stream>>>(o1a, wo1t, bo1, x, x2, 4096, 320, 320);
  // --- attn2 (sim2 path: fp32-emulated MFMA throughout) ---
  ln2_split_kernel<<<1024, 256, 0, stream>>>(x2, g2, b2, h2hi, h2lo);
  gemm3_64_kernel<<<dim3(64,5), 256, 0, stream>>>(h2hi, h2lo, wq2th, wq2tl, q2, 4096, 320, 320);
  kv2_dot_kernel<<<3080, 256, 0, stream>>>(ctx, wkv2t, kv2);
  kv2_post_kernel<<<336, 256, 0, stream>>>(kv2, k2h, k2l, v2t);
  attn_cross_kernel<<<dim3(64,8), 256, 0, stream>>>(q2, k2h, k2l, famh, faml, v2t, ufca, o2);
  gemm_bf16_64_kernel<0><<<dim3(64,5), 256, 0, stream>>>(o2, wo2t, bo2, x2, x3, 4096, 320, 320);
  // --- GEGLU FF ---
  ln_kernel<bf16_t><<<1024, 256, 0, stream>>>(x3, g3, b3, h3b);
  gemm_bf16_kernel<1><<<dim3(32,40), 256, 0, stream>>>(h3b, wff1t, bff1, nullptr, proj, 4096, 2560, 320);
  geglu_kernel<<<5120, 256, 0, stream>>>(proj, gg);
  gemm_bf16_64_kernel<0><<<dim3(64,5), 256, 0, stream>>>(gg, wff2t, bff2, x3, xout, 4096, 320, 1280);
}

// Round 11
// 317.480 us; speedup vs baseline: 1.2538x; 1.0842x over previous
//
#include <hip/hip_runtime.h>
#include <math.h>

typedef __bf16 bf16_t;
typedef __bf16 bf16x8 __attribute__((ext_vector_type(8)));
typedef __bf16 bf16x4 __attribute__((ext_vector_type(4)));
typedef float  f32x4  __attribute__((ext_vector_type(4)));
typedef _Float16 f16_t;
typedef _Float16 f16x4 __attribute__((ext_vector_type(4)));
typedef __fp16 hf16x2 __attribute__((ext_vector_type(2)));

static constexpr float ATT_SCALE = 0.15811388300841897f; // 40^-0.5
static constexpr float SC2 = 0.22811031f;                // ATT_SCALE * log2(e)
static constexpr float LOG2E = 1.4426950408889634f;

__device__ __forceinline__ bf16_t f2b(float f) {
  unsigned u = __float_as_uint(f);
  u = (u + 0x7fffu + ((u >> 16) & 1u)) >> 16;   // RNE
  unsigned short s = (unsigned short)u;
  bf16_t r;
  *(unsigned short*)&r = s;
  return r;
}
__device__ __forceinline__ float b2f(bf16_t b) {
  unsigned short s = *(const unsigned short*)&b;
  return __uint_as_float(((unsigned)s) << 16);
}
__device__ __forceinline__ void sto(float v, float* p)  { *p = v; }
__device__ __forceinline__ void sto(float v, bf16_t* p) { *p = f2b(v); }
__device__ __forceinline__ unsigned pkh2(float a, float b) {
  hf16x2 h = __builtin_amdgcn_cvt_pkrtz(a, b);
  return *(unsigned*)&h;
}

// =========================== weight repack ===========================
__global__ __launch_bounds__(256) void prep_kernel(
    const float* __restrict__ Wq1, const float* __restrict__ Wk1, const float* __restrict__ Wv1,
    const float* __restrict__ Wo1, const float* __restrict__ Wq2,
    const float* __restrict__ Wk2, const float* __restrict__ Wv2, const float* __restrict__ Wo2,
    const float* __restrict__ Wff1, const float* __restrict__ Wff2,
    const float* __restrict__ fam,
    bf16_t* __restrict__ wqkvt, bf16_t* __restrict__ wo1t, float* __restrict__ wkv2t,
    bf16_t* __restrict__ wo2t, bf16_t* __restrict__ wff1t, bf16_t* __restrict__ wff2t,
    bf16_t* __restrict__ wq2th, bf16_t* __restrict__ wq2tl,
    bf16_t* __restrict__ famh, bf16_t* __restrict__ faml)
{
  const int T1 = 960*320;
  const int T2 = T1 + 320*320;
  const int T3 = T2 + 768*640;
  const int T4 = T3 + 320*320;
  const int T5 = T4 + 2560*320;
  const int T6 = T5 + 320*1280;
  const int T7 = T6 + 320*320;
  const int T8 = T7 + 96*96;
  for (int i = blockIdx.x*256 + threadIdx.x; i < T8; i += gridDim.x*256) {
    if (i < T1) {
      int n = i / 320, k = i - n*320;
      float v = (n < 320) ? Wq1[k*320+n] * SC2
              : (n < 640) ? Wk1[k*320+n-320] : Wv1[k*320+n-640];
      wqkvt[i] = f2b(v);
    } else if (i < T2) {
      int e = i - T1; int n = e / 320, k = e - n*320;
      wo1t[e] = f2b(Wo1[k*320+n]);
    } else if (i < T3) {
      int e = i - T2; int n = e / 768, k = e - n*768;
      wkv2t[e] = (n < 320) ? Wk2[k*320+n] : Wv2[k*320+n-320];
    } else if (i < T4) {
      int e = i - T3; int n = e / 320, k = e - n*320;
      wo2t[e] = f2b(Wo2[k*320+n]);
    } else if (i < T5) {
      int e = i - T4; int n = e / 320, k = e - n*320;
      wff1t[e] = f2b(Wff1[(size_t)k*2560+n]);
    } else if (i < T6) {
      int e = i - T5; int n = e / 1280, k = e - n*1280;
      wff2t[e] = f2b(Wff2[k*320+n]);
    } else if (i < T7) {
      int e = i - T6; int n = e / 320, k = e - n*320;
      float v = Wq2[k*320+n];
      bf16_t h = f2b(v);
      wq2th[e] = h;
      wq2tl[e] = f2b(v - b2f(h));
    } else {
      int e = i - T7; int d = e / 96, k = e - d*96;
      float v = (d < 77 && k < 77) ? fam[d*77 + k] : 0.f;
      bf16_t h = f2b(v);
      famh[e] = h;
      faml[e] = f2b(v - b2f(h));
    }
  }
}

// =========================== LayerNorm ===========================
template<typename OT>
__global__ __launch_bounds__(256) void ln_kernel(
    const float* __restrict__ x, const float* __restrict__ g, const float* __restrict__ b,
    OT* __restrict__ out)
{
  const int lane = threadIdx.x & 63;
  const int row = blockIdx.x * 4 + (threadIdx.x >> 6);
  const float* xr = x + (size_t)row * 320;
  float v[5], s = 0.f, s2 = 0.f;
#pragma unroll
  for (int i = 0; i < 5; i++) { v[i] = xr[lane + i*64]; s += v[i]; s2 += v[i]*v[i]; }
#pragma unroll
  for (int o = 32; o; o >>= 1) { s += __shfl_xor(s, o); s2 += __shfl_xor(s2, o); }
  float mu = s * (1.f/320.f);
  float rs = rsqrtf(fmaxf(s2*(1.f/320.f) - mu*mu, 0.f) + 1e-5f);
#pragma unroll
  for (int i = 0; i < 5; i++) {
    int c = lane + i*64;
    sto((v[i]-mu)*rs*g[c] + b[c], &out[(size_t)row*320 + c]);
  }
}

// LayerNorm writing hi/lo bf16 split
__global__ __launch_bounds__(256) void ln2_split_kernel(
    const float* __restrict__ x, const float* __restrict__ g, const float* __restrict__ b,
    bf16_t* __restrict__ hi, bf16_t* __restrict__ lo)
{
  const int lane = threadIdx.x & 63;
  const int row = blockIdx.x * 4 + (threadIdx.x >> 6);
  const float* xr = x + (size_t)row * 320;
  float v[5], s = 0.f, s2 = 0.f;
#pragma unroll
  for (int i = 0; i < 5; i++) { v[i] = xr[lane + i*64]; s += v[i]; s2 += v[i]*v[i]; }
#pragma unroll
  for (int o = 32; o; o >>= 1) { s += __shfl_xor(s, o); s2 += __shfl_xor(s2, o); }
  float mu = s * (1.f/320.f);
  float rs = rsqrtf(fmaxf(s2*(1.f/320.f) - mu*mu, 0.f) + 1e-5f);
#pragma unroll
  for (int i = 0; i < 5; i++) {
    int c = lane + i*64;
    float y = (v[i]-mu)*rs*g[c] + b[c];
    bf16_t h = f2b(y);
    hi[(size_t)row*320 + c] = h;
    lo[(size_t)row*320 + c] = f2b(y - b2f(h));
  }
}

// =========================== kv2 dot-product GEMM ===========================
__global__ __launch_bounds__(256) void kv2_dot_kernel(
    const float* __restrict__ ctx, const float* __restrict__ wkv2t, float* __restrict__ kv2)
{
  const int gid = blockIdx.x*16 + (threadIdx.x >> 4);
  const int q = threadIdx.x & 15;
  const int m = gid / 640, n = gid - m*640;
  const float4* a = (const float4*)(ctx + (size_t)m*768);
  const float4* b = (const float4*)(wkv2t + (size_t)n*768);
  float acc = 0.f;
#pragma unroll
  for (int i = 0; i < 12; i++) {
    float4 av = a[i*16+q], bv = b[i*16+q];
    acc += av.x*bv.x + av.y*bv.y + av.z*bv.z + av.w*bv.w;
  }
#pragma unroll
  for (int o = 8; o; o >>= 1) acc += __shfl_xor(acc, o);
  if (q == 0) kv2[(size_t)m*640 + n] = acc;
}

// =========================== kv2 post: K2 hi/lo and V^T ===========================
__global__ __launch_bounds__(256) void kv2_post_kernel(
    const float* __restrict__ kv2, bf16_t* __restrict__ k2h, bf16_t* __restrict__ k2l,
    bf16_t* __restrict__ v2t)
{
  const int NK = 8*96*64;
  const int NV = 8*48*96;
  int i = blockIdx.x*256 + threadIdx.x;
  if (i < NK) {
    int h = i / (96*64), r = i - h*96*64, j = r >> 6, d = r & 63;
    float v = (j < 77 && d < 40) ? kv2[(size_t)j*640 + h*40 + d] : 0.f;
    bf16_t hh = f2b(v);
    k2h[i] = hh;
    k2l[i] = f2b(v - b2f(hh));
  } else if (i < NK + NV) {
    int e = i - NK;
    int h = e / (48*96), r = e - h*48*96, d = r / 96, j = r - d*96;
    v2t[e] = f2b((d < 40 && j < 77) ? kv2[(size_t)j*640 + 320 + h*40 + d] : 0.f);
  }
}

// =========================== V^T repack (self-attn): f16, 48 rows, row 40 = ones ===========================
__global__ __launch_bounds__(256) void repack_vt_kernel(
    const bf16_t* __restrict__ qkvb, f16_t* __restrict__ vtg)
{
  __shared__ f16_t T[64*44];
  const int tid = threadIdx.x;
  const int t0 = blockIdx.x * 64, h = blockIdx.y;
  for (int e = tid; e < 320; e += 256) {
    int t = e / 5, c8 = (e - t*5) * 8;
    bf16x8 v = *(const bf16x8*)(qkvb + (size_t)(t0+t)*960 + 640 + h*40 + c8);
    f16_t* dst = &T[t*44 + c8];
#pragma unroll
    for (int j = 0; j < 8; j++) dst[j] = (f16_t)b2f(v[j]);
  }
  __syncthreads();
  for (int e = tid; e < 320; e += 256) {
    int d = e >> 3, t8 = (e & 7) * 8;
    f16_t* dst = vtg + ((size_t)h*48 + d)*4096 + t0 + t8;
#pragma unroll
    for (int j = 0; j < 8; j++) dst[j] = T[(t8+j)*44 + d];
  }
  for (int e = tid; e < 512; e += 256) {
    int r = 40 + (e >> 6), t = e & 63;
    vtg[((size_t)h*48 + r)*4096 + t0 + t] = (r == 40) ? (f16_t)1.0f : (f16_t)0.0f;
  }
}

// =========================== bf16/f16 MFMA flash self-attention (v4 + XCD swizzle) ===========================
// grid (512, 2): blockIdx.x = qb*8 + h  =>  h = x & 7 is the fastest-varying coordinate, so under
// round-robin block->XCD dispatch each XCD serves ~one head and K/V stay L2-resident (~360 KB/XCD).
__global__ __launch_bounds__(256, 4) void flash_self_kernel(
    const bf16_t* __restrict__ qkvb, const f16_t* __restrict__ vtg,
    float* __restrict__ opart, float* __restrict__ lpart)
{
  __shared__ float Red[6144];      // 24 KB, two-pass epilogue
  const int tid = threadIdx.x;
  const int w = tid >> 6, lane = tid & 63;
  const int ln = lane & 15, qd = lane >> 4;
  const int h = blockIdx.x & 7;
  const int q0 = (blockIdx.x >> 3) * 64;
  const int split = blockIdx.y;

  bf16x8 zero8 = {};
  bf16x8 bq[4][2];
#pragma unroll
  for (int nt = 0; nt < 4; nt++) {
    const bf16_t* qp = qkvb + (size_t)(q0 + nt*16 + ln)*960 + h*40;
    bq[nt][0] = *(const bf16x8*)(qp + qd*8);
    bq[nt][1] = (qd == 0) ? *(const bf16x8*)(qp + 32) : zero8;
  }

  f32x4 zero4 = {0.f,0.f,0.f,0.f};
  f32x4 oacc[3][4];
#pragma unroll
  for (int a = 0; a < 3; a++)
#pragma unroll
    for (int b = 0; b < 4; b++) oacc[a][b] = zero4;

  const bf16_t* kbase = qkvb + 320 + h*40 + (size_t)(w*16 + ln)*960;
  const f16_t*  vrow  = vtg + (size_t)h*48*4096 + (size_t)ln*4096 + w*16 + qd*4;

  const bf16_t* kp0 = kbase + (size_t)(split*2048)*960;
  bf16x8 ka0 = *(const bf16x8*)(kp0 + qd*8);
  bf16x8 ka1 = (qd == 0) ? *(const bf16x8*)(kp0 + 32) : zero8;

  for (int kt = 0; kt < 32; kt++) {
    int k0 = split*2048 + kt*64;
    bf16x8 nka0 = zero8, nka1 = zero8;
    if (kt < 31) {
      const bf16_t* kpn = kbase + (size_t)(k0 + 64)*960;
      nka0 = *(const bf16x8*)(kpn + qd*8);
      if (qd == 0) nka1 = *(const bf16x8*)(kpn + 32);
    }

    f16x4 pb[4];
#pragma unroll
    for (int nt = 0; nt < 4; nt++) {
      f32x4 s = __builtin_amdgcn_mfma_f32_16x16x32_bf16(ka0, bq[nt][0], zero4, 0, 0, 0);
      s = __builtin_amdgcn_mfma_f32_16x16x32_bf16(ka1, bq[nt][1], s, 0, 0, 0);
      uint2 u;
      u.x = pkh2(__builtin_amdgcn_exp2f(s[0]), __builtin_amdgcn_exp2f(s[1]));
      u.y = pkh2(__builtin_amdgcn_exp2f(s[2]), __builtin_amdgcn_exp2f(s[3]));
      pb[nt] = *(f16x4*)&u;
    }
#pragma unroll
    for (int dt = 0; dt < 3; dt++) {
      f16x4 va = *(const f16x4*)(vrow + (size_t)dt*16*4096 + k0);
#pragma unroll
      for (int nt = 0; nt < 4; nt++)
        oacc[dt][nt] = __builtin_amdgcn_mfma_f32_16x16x16f16(va, pb[nt], oacc[dt][nt], 0, 0, 0);
    }
    ka0 = nka0;
    ka1 = nka1;
  }

  // ---- epilogue: two-pass cross-wave (key-slice) reduction via LDS ----
  float* obase = opart + ((size_t)(split*8 + h)*4096 + q0)*40;
  for (int np = 0; np < 2; np++) {
    __syncthreads();
#pragma unroll
    for (int e = 0; e < 2; e++) {
      int nt = np*2 + e;
#pragma unroll
      for (int dt = 0; dt < 3; dt++)
        *(f32x4*)&Red[((w*2 + e)*3 + dt)*256 + ln*16 + qd*4] = oacc[dt][nt];
    }
    __syncthreads();
    int e = tid >> 7;
    int lq = (tid >> 3) & 15;
    int dbase = tid & 7;
#pragma unroll
    for (int i = 0; i < 5; i++) {
      int d = dbase + i*8;
      int dt = d >> 4, drow = d & 15;
      float v = Red[((0*2+e)*3 + dt)*256 + lq*16 + drow]
              + Red[((1*2+e)*3 + dt)*256 + lq*16 + drow]
              + Red[((2*2+e)*3 + dt)*256 + lq*16 + drow]
              + Red[((3*2+e)*3 + dt)*256 + lq*16 + drow];
      obase[(size_t)((np*2+e)*16 + lq)*40 + d] = v;
    }
    if (dbase == 0) {
      float l = Red[((0*2+e)*3 + 2)*256 + lq*16 + 8]
              + Red[((1*2+e)*3 + 2)*256 + lq*16 + 8]
              + Red[((2*2+e)*3 + 2)*256 + lq*16 + 8]
              + Red[((3*2+e)*3 + 2)*256 + lq*16 + 8];
      lpart[(size_t)(split*8 + h)*4096 + q0 + (np*2+e)*16 + lq] = l;
    }
  }
}

// =========================== merge K-split partials (2 splits, f32 opart) ===========================
__global__ __launch_bounds__(256) void merge_o1_kernel(
    const float* __restrict__ op, const float* __restrict__ lp, bf16_t* __restrict__ o1a)
{
  int i = blockIdx.x*256 + threadIdx.x;
  int q = i / 320, c = i - q*320;
  int h = c / 40, d = c - h*40;
  size_t base = ((size_t)h*4096 + q)*40 + d;
  float l = lp[h*4096 + q] + lp[32768 + h*4096 + q];
  float o = op[base] + op[base + 1310720];
  o1a[i] = f2b(o / l);
}

// =========================== cross-attention (all-MFMA, single-pass, no barriers; XCD swizzle) ===========================
// grid (512): blockIdx.x = qb*8 + h
__global__ __launch_bounds__(256) void attn_cross_kernel(
    const float* __restrict__ q2, const bf16_t* __restrict__ k2h, const bf16_t* __restrict__ k2l,
    const bf16_t* __restrict__ famh, const bf16_t* __restrict__ faml,
    const bf16_t* __restrict__ v2t, const int* __restrict__ use_fca,
    bf16_t* __restrict__ o2)
{
  __shared__ bf16_t SMh[4][16*96];
  __shared__ bf16_t SMl[4][16*96];
  __shared__ bf16_t PAs[4][16*96];
  const int tid = threadIdx.x;
  const int w = tid >> 6, lane = tid & 63;
  const int ln = lane & 15, qd = lane >> 4;
  const int h = blockIdx.x & 7;
  const int q0 = (blockIdx.x >> 3)*64 + w*16;
  const int fca = use_fca[0];
  bf16_t* smh = SMh[w];
  bf16_t* sml = SMl[w];
  bf16_t* pa  = PAs[w];

  {
    bf16x4 z = {};
    int q = lane >> 2, c = 80 + (lane & 3)*4;
    *(bf16x4*)&smh[q*96 + c] = z;
    *(bf16x4*)&sml[q*96 + c] = z;
    *(bf16x4*)&pa [q*96 + c] = z;
  }

  bf16x8 zero8 = {};
  bf16x8 aqh0, aql0, aqh1 = zero8, aql1 = zero8;
  {
    const float* qp = q2 + (size_t)(q0 + ln)*320 + h*40;
    float4 v0 = *(const float4*)(qp + qd*8);
    float4 v1 = *(const float4*)(qp + qd*8 + 4);
    float qv[8] = {v0.x,v0.y,v0.z,v0.w,v1.x,v1.y,v1.z,v1.w};
#pragma unroll
    for (int i = 0; i < 8; i++) {
      bf16_t hh = f2b(qv[i]);
      aqh0[i] = hh; aql0[i] = f2b(qv[i] - b2f(hh));
    }
    if (qd == 0) {
      float4 u0 = *(const float4*)(qp + 32);
      float4 u1 = *(const float4*)(qp + 36);
      float uv[8] = {u0.x,u0.y,u0.z,u0.w,u1.x,u1.y,u1.z,u1.w};
#pragma unroll
      for (int i = 0; i < 8; i++) {
        bf16_t hh = f2b(uv[i]);
        aqh1[i] = hh; aql1[i] = f2b(uv[i] - b2f(hh));
      }
    }
  }

  f32x4 zero4 = {0.f,0.f,0.f,0.f};
  float ss[5][4];
#pragma unroll
  for (int nt = 0; nt < 5; nt++) {
    const bf16_t* kb = k2h + ((size_t)h*96 + nt*16 + ln)*64 + qd*8;
    const bf16_t* kl = k2l + ((size_t)h*96 + nt*16 + ln)*64 + qd*8;
    bf16x8 kh0 = *(const bf16x8*)kb;
    bf16x8 kh1 = *(const bf16x8*)(kb + 32);
    bf16x8 kl0 = *(const bf16x8*)kl;
    bf16x8 kl1 = *(const bf16x8*)(kl + 32);
    f32x4 s;
    s = __builtin_amdgcn_mfma_f32_16x16x32_bf16(aqh0, kl0, zero4, 0, 0, 0);
    s = __builtin_amdgcn_mfma_f32_16x16x32_bf16(aql0, kh0, s, 0, 0, 0);
    s = __builtin_amdgcn_mfma_f32_16x16x32_bf16(aqh0, kh0, s, 0, 0, 0);
    s = __builtin_amdgcn_mfma_f32_16x16x32_bf16(aqh1, kl1, s, 0, 0, 0);
    s = __builtin_amdgcn_mfma_f32_16x16x32_bf16(aql1, kh1, s, 0, 0, 0);
    s = __builtin_amdgcn_mfma_f32_16x16x32_bf16(aqh1, kh1, s, 0, 0, 0);
#pragma unroll
    for (int r = 0; r < 4; r++) {
      float sv = s[r] * ATT_SCALE;
      ss[nt][r] = sv;
      bf16_t hh = f2b(sv);
      smh[(qd*4 + r)*96 + nt*16 + ln] = hh;
      sml[(qd*4 + r)*96 + nt*16 + ln] = f2b(sv - b2f(hh));
    }
  }

  f32x4 facc[5];
#pragma unroll
  for (int nt = 0; nt < 5; nt++) facc[nt] = zero4;
#pragma unroll
  for (int c = 0; c < 3; c++) {
    bf16x8 sah = *(const bf16x8*)&smh[ln*96 + c*32 + qd*8];
    bf16x8 sal = *(const bf16x8*)&sml[ln*96 + c*32 + qd*8];
#pragma unroll
    for (int nt = 0; nt < 5; nt++) {
      bf16x8 fh8 = *(const bf16x8*)(famh + ((size_t)(nt*16 + ln))*96 + c*32 + qd*8);
      bf16x8 fl8 = *(const bf16x8*)(faml + ((size_t)(nt*16 + ln))*96 + c*32 + qd*8);
      facc[nt] = __builtin_amdgcn_mfma_f32_16x16x32_bf16(sah, fl8, facc[nt], 0, 0, 0);
      facc[nt] = __builtin_amdgcn_mfma_f32_16x16x32_bf16(sal, fh8, facc[nt], 0, 0, 0);
      facc[nt] = __builtin_amdgcn_mfma_f32_16x16x32_bf16(sah, fh8, facc[nt], 0, 0, 0);
    }
  }

  float pr[5][4];
  if (fca) {
    float fwv[5][4], fm[4];
#pragma unroll
    for (int nt = 0; nt < 5; nt++)
#pragma unroll
      for (int r = 0; r < 4; r++) fwv[nt][r] = fminf(fabsf(facc[nt][r]), 1.f);
#pragma unroll
    for (int r = 0; r < 4; r++) {
      float m = fmaxf(fmaxf(fwv[0][r], fwv[1][r]), fmaxf(fwv[2][r], fmaxf(fwv[3][r], fwv[4][r])));
#pragma unroll
      for (int o = 8; o; o >>= 1) m = fmaxf(m, __shfl_xor(m, o));
      fm[r] = m;
    }
#pragma unroll
    for (int nt = 0; nt < 5; nt++)
#pragma unroll
      for (int r = 0; r < 4; r++) {
        float lg = ss[nt][r] - ((fwv[nt][r] > 0.6f*(fm[r] + 1e-6f)) ? 0.f : 50.f);
        pr[nt][r] = __builtin_amdgcn_exp2f(lg * LOG2E);
      }
  } else {
#pragma unroll
    for (int nt = 0; nt < 5; nt++)
#pragma unroll
      for (int r = 0; r < 4; r++)
        pr[nt][r] = __builtin_amdgcn_exp2f(ss[nt][r] * LOG2E);
  }
  if (ln >= 13) {
#pragma unroll
    for (int r = 0; r < 4; r++) pr[4][r] = 0.f;
  }
  float l_[4] = {0.f,0.f,0.f,0.f};
#pragma unroll
  for (int nt = 0; nt < 5; nt++)
#pragma unroll
    for (int r = 0; r < 4; r++) {
      l_[r] += pr[nt][r];
      pa[(qd*4 + r)*96 + nt*16 + ln] = f2b(pr[nt][r]);
    }
#pragma unroll
  for (int r = 0; r < 4; r++)
#pragma unroll
    for (int o = 8; o; o >>= 1) l_[r] += __shfl_xor(l_[r], o);

  f32x4 oacc[3];
#pragma unroll
  for (int nt = 0; nt < 3; nt++) oacc[nt] = zero4;
#pragma unroll
  for (int c = 0; c < 3; c++) {
    bf16x8 paf = *(const bf16x8*)&pa[ln*96 + c*32 + qd*8];
#pragma unroll
    for (int nt = 0; nt < 3; nt++) {
      bf16x8 vb = *(const bf16x8*)(v2t + ((size_t)h*48 + nt*16 + ln)*96 + c*32 + qd*8);
      oacc[nt] = __builtin_amdgcn_mfma_f32_16x16x32_bf16(paf, vb, oacc[nt], 0, 0, 0);
    }
  }
  float inv[4];
#pragma unroll
  for (int r = 0; r < 4; r++) inv[r] = 1.f / l_[r];
#pragma unroll
  for (int nt = 0; nt < 3; nt++) {
    int d = nt*16 + ln;
    if (d < 40) {
#pragma unroll
      for (int r = 0; r < 4; r++)
        o2[(size_t)(q0 + qd*4 + r)*320 + h*40 + d] = f2b(oacc[nt][r]*inv[r]);
    }
  }
}

// =========================== bf16 MFMA GEMM 128x64 ===========================
template<int OUT_BF16>
__global__ __launch_bounds__(256) void gemm_bf16_kernel(
    const bf16_t* __restrict__ A, const bf16_t* __restrict__ Bt,
    const float* __restrict__ bias, const float* __restrict__ resid,
    void* __restrict__ Cout, int M, int N, int K)
{
  __shared__ bf16_t As[128][72];
  __shared__ bf16_t Bs[64][72];
  const int tid = threadIdx.x;
  const int m0 = blockIdx.x * 128, n0 = blockIdx.y * 64;
  const int w = tid >> 6, lane = tid & 63;
  const int wr = w >> 1, wc = w & 1;
  const int ln = lane & 15, qd = lane >> 4;
  f32x4 zero = {0.f, 0.f, 0.f, 0.f};
  f32x4 acc[4][2];
#pragma unroll
  for (int a = 0; a < 4; a++)
#pragma unroll
    for (int b = 0; b < 2; b++) acc[a][b] = zero;

  for (int k0 = 0; k0 < K; k0 += 64) {
    __syncthreads();
#pragma unroll
    for (int i = 0; i < 4; i++) {
      int vid = tid + i*256;
      int r = vid >> 3, c8 = (vid & 7) * 8;
      *(bf16x8*)&As[r][c8] = *(const bf16x8*)(A + (size_t)(m0+r)*K + k0 + c8);
    }
#pragma unroll
    for (int i = 0; i < 2; i++) {
      int vid = tid + i*256;
      int r = vid >> 3, c8 = (vid & 7) * 8;
      *(bf16x8*)&Bs[r][c8] = *(const bf16x8*)(Bt + (size_t)(n0+r)*K + k0 + c8);
    }
    __syncthreads();
#pragma unroll
    for (int c = 0; c < 2; c++) {
      bf16x8 af[4], bfr[2];
#pragma unroll
      for (int mt = 0; mt < 4; mt++)
        af[mt] = *(const bf16x8*)&As[wr*64 + mt*16 + ln][c*32 + qd*8];
#pragma unroll
      for (int nt = 0; nt < 2; nt++)
        bfr[nt] = *(const bf16x8*)&Bs[wc*32 + nt*16 + ln][c*32 + qd*8];
#pragma unroll
      for (int mt = 0; mt < 4; mt++)
#pragma unroll
        for (int nt = 0; nt < 2; nt++)
          acc[mt][nt] = __builtin_amdgcn_mfma_f32_16x16x32_bf16(af[mt], bfr[nt], acc[mt][nt], 0, 0, 0);
    }
  }
#pragma unroll
  for (int mt = 0; mt < 4; mt++)
#pragma unroll
    for (int nt = 0; nt < 2; nt++)
#pragma unroll
      for (int r = 0; r < 4; r++) {
        int gm = m0 + wr*64 + mt*16 + qd*4 + r;
        int gn = n0 + wc*32 + nt*16 + ln;
        float v = acc[mt][nt][r];
        if (bias)  v += bias[gn];
        if (resid) v += resid[(size_t)gm*N + gn];
        if (OUT_BF16) sto(v, &((bf16_t*)Cout)[(size_t)gm*N + gn]);
        else          sto(v, &((float*)Cout)[(size_t)gm*N + gn]);
      }
}

// =========================== bf16 MFMA GEMM 32x64 (4x block count for narrow GEMMs) ===========================
template<int OUT_BF16>
__global__ __launch_bounds__(256) void gemm_bf16_32_kernel(
    const bf16_t* __restrict__ A, const bf16_t* __restrict__ Bt,
    const float* __restrict__ bias, const float* __restrict__ resid,
    void* __restrict__ Cout, int M, int N, int K)
{
  __shared__ bf16_t As[32][72];
  __shared__ bf16_t Bs[64][72];
  const int tid = threadIdx.x;
  const int m0 = blockIdx.x * 32, n0 = blockIdx.y * 64;
  const int w = tid >> 6, lane = tid & 63;
  const int wr = w >> 1, wc = w & 1;      // wave tile: 16 rows x 32 cols
  const int ln = lane & 15, qd = lane >> 4;
  f32x4 zero = {0.f, 0.f, 0.f, 0.f};
  f32x4 acc[2];
  acc[0] = zero; acc[1] = zero;

  for (int k0 = 0; k0 < K; k0 += 64) {
    __syncthreads();
    {
      int r = tid >> 3, c8 = (tid & 7) * 8;   // 32 rows x 64 cols = 256 chunks
      *(bf16x8*)&As[r][c8] = *(const bf16x8*)(A + (size_t)(m0+r)*K + k0 + c8);
    }
#pragma unroll
    for (int i = 0; i < 2; i++) {
      int vid = tid + i*256;
      int r = vid >> 3, c8 = (vid & 7) * 8;
      *(bf16x8*)&Bs[r][c8] = *(const bf16x8*)(Bt + (size_t)(n0+r)*K + k0 + c8);
    }
    __syncthreads();
#pragma unroll
    for (int c = 0; c < 2; c++) {
      bf16x8 af = *(const bf16x8*)&As[wr*16 + ln][c*32 + qd*8];
#pragma unroll
      for (int nt = 0; nt < 2; nt++) {
        bf16x8 bfr = *(const bf16x8*)&Bs[wc*32 + nt*16 + ln][c*32 + qd*8];
        acc[nt] = __builtin_amdgcn_mfma_f32_16x16x32_bf16(af, bfr, acc[nt], 0, 0, 0);
      }
    }
  }
#pragma unroll
  for (int nt = 0; nt < 2; nt++)
#pragma unroll
    for (int r = 0; r < 4; r++) {
      int gm = m0 + wr*16 + qd*4 + r;
      int gn = n0 + wc*32 + nt*16 + ln;
      float v = acc[nt][r];
      if (bias)  v += bias[gn];
      if (resid) v += resid[(size_t)gm*N + gn];
      if (OUT_BF16) sto(v, &((bf16_t*)Cout)[(size_t)gm*N + gn]);
      else          sto(v, &((float*)Cout)[(size_t)gm*N + gn]);
    }
}

// =========================== 3-term bf16 MFMA GEMM (fp32 emulation), 32x64 tile ===========================
__global__ __launch_bounds__(256) void gemm3_32_kernel(
    const bf16_t* __restrict__ Ah, const bf16_t* __restrict__ Al,
    const bf16_t* __restrict__ Bth, const bf16_t* __restrict__ Btl,
    float* __restrict__ C, int M, int N, int K)
{
  __shared__ bf16_t Ash[32][72];
  __shared__ bf16_t Asl[32][72];
  __shared__ bf16_t Bsh[64][72];
  __shared__ bf16_t Bsl[64][72];
  const int tid = threadIdx.x;
  const int m0 = blockIdx.x * 32, n0 = blockIdx.y * 64;
  const int w = tid >> 6, lane = tid & 63;
  const int wr = w >> 1, wc = w & 1;
  const int ln = lane & 15, qd = lane >> 4;
  f32x4 zero = {0.f, 0.f, 0.f, 0.f};
  f32x4 acc[2];
  acc[0] = zero; acc[1] = zero;

  for (int k0 = 0; k0 < K; k0 += 64) {
    __syncthreads();
    {
      int r = tid >> 3, c8 = (tid & 7) * 8;
      *(bf16x8*)&Ash[r][c8] = *(const bf16x8*)(Ah + (size_t)(m0+r)*K + k0 + c8);
      *(bf16x8*)&Asl[r][c8] = *(const bf16x8*)(Al + (size_t)(m0+r)*K + k0 + c8);
    }
#pragma unroll
    for (int i = 0; i < 2; i++) {
      int vid = tid + i*256;
      int r = vid >> 3, c8 = (vid & 7) * 8;
      *(bf16x8*)&Bsh[r][c8] = *(const bf16x8*)(Bth + (size_t)(n0+r)*K + k0 + c8);
      *(bf16x8*)&Bsl[r][c8] = *(const bf16x8*)(Btl + (size_t)(n0+r)*K + k0 + c8);
    }
    __syncthreads();
#pragma unroll
    for (int c = 0; c < 2; c++) {
      bf16x8 afh = *(const bf16x8*)&Ash[wr*16 + ln][c*32 + qd*8];
      bf16x8 afl = *(const bf16x8*)&Asl[wr*16 + ln][c*32 + qd*8];
#pragma unroll
      for (int nt = 0; nt < 2; nt++) {
        bf16x8 bfh = *(const bf16x8*)&Bsh[wc*32 + nt*16 + ln][c*32 + qd*8];
        bf16x8 bfl = *(const bf16x8*)&Bsl[wc*32 + nt*16 + ln][c*32 + qd*8];
        acc[nt] = __builtin_amdgcn_mfma_f32_16x16x32_bf16(afh, bfl, acc[nt], 0, 0, 0);
        acc[nt] = __builtin_amdgcn_mfma_f32_16x16x32_bf16(afl, bfh, acc[nt], 0, 0, 0);
        acc[nt] = __builtin_amdgcn_mfma_f32_16x16x32_bf16(afh, bfh, acc[nt], 0, 0, 0);
      }
    }
  }
#pragma unroll
  for (int nt = 0; nt < 2; nt++)
#pragma unroll
    for (int r = 0; r < 4; r++) {
      int gm = m0 + wr*16 + qd*4 + r;
      int gn = n0 + wc*32 + nt*16 + ln;
      C[(size_t)gm*N + gn] = acc[nt][r];
    }
}

// =========================== GEGLU ===========================
__global__ __launch_bounds__(256) void geglu_kernel(
    const bf16_t* __restrict__ proj, bf16_t* __restrict__ gg)
{
  int idx = blockIdx.x * 256 + threadIdx.x;
  int m = idx / 320, c4 = (idx - m*320) * 4;
  bf16x4 a = *(const bf16x4*)(proj + (size_t)m*2560 + c4);
  bf16x4 g = *(const bf16x4*)(proj + (size_t)m*2560 + 1280 + c4);
  bf16x4 r;
#pragma unroll
  for (int i = 0; i < 4; i++) {
    float gf = b2f(g[i]);
    float ge = 0.5f * gf * (1.f + erff(gf * 0.70710678118654752f));
    r[i] = f2b(b2f(a[i]) * ge);
  }
  *(bf16x4*)(gg + (size_t)m*1280 + c4) = r;
}

// =========================== launch ===========================
extern "C" void kernel_launch(void* const* d_in, const int* in_sizes, int n_in,
                              void* d_out, int out_size, void* d_ws, size_t ws_size,
                              hipStream_t stream)
{
  const float* x    = (const float*)d_in[0];
  const float* ctx  = (const float*)d_in[1];
  const float* fam  = (const float*)d_in[2];
  const float* g1   = (const float*)d_in[3];
  const float* b1   = (const float*)d_in[4];
  const float* g2   = (const float*)d_in[5];
  const float* b2   = (const float*)d_in[6];
  const float* g3   = (const float*)d_in[7];
  const float* b3   = (const float*)d_in[8];
  const float* Wq1  = (const float*)d_in[9];
  const float* Wk1  = (const float*)d_in[10];
  const float* Wv1  = (const float*)d_in[11];
  const float* Wo1  = (const float*)d_in[12];
  const float* bo1  = (const float*)d_in[13];
  const float* Wq2  = (const float*)d_in[14];
  const float* Wk2  = (const float*)d_in[15];
  const float* Wv2  = (const float*)d_in[16];
  const float* Wo2  = (const float*)d_in[17];
  const float* bo2  = (const float*)d_in[18];
  const float* Wff1 = (const float*)d_in[19];
  const float* bff1 = (const float*)d_in[20];
  const float* Wff2 = (const float*)d_in[21];
  const float* bff2 = (const float*)d_in[22];
  const int*   ufca = (const int*)d_in[23];

  char* ws = (char*)d_ws;
  bf16_t* qkvb = (bf16_t*)(ws + 0);          //  7,864,320  bf16 [4096][960] (Q pre-scaled)
  f16_t*  vtg  = (f16_t*)(ws + 7864320);     //  3,145,728  f16 [8][48][4096] (row40=1)
  bf16_t* o1a  = (bf16_t*)(ws + 11010048);   //  2,621,440  bf16 [4096][320]
  bf16_t* h1b  = (bf16_t*)(ws + 13631488);   //  2,621,440
  bf16_t* h2hi = (bf16_t*)(ws + 16252928);   //  2,621,440
  bf16_t* h2lo = (bf16_t*)(ws + 18874368);   //  2,621,440
  float*  x2   = (float*)(ws + 21495808);    //  5,242,880
  float*  q2   = (float*)(ws + 26738688);    //  5,242,880
  float*  kv2  = (float*)(ws + 31981568);    //    197,120
  bf16_t* o2   = (bf16_t*)(ws + 32178688);   //  2,621,440
  float*  x3   = (float*)(ws + 34800128);    //  5,242,880
  bf16_t* h3b  = (bf16_t*)(ws + 40043008);   //  2,621,440
  bf16_t* wqkvt = (bf16_t*)(ws + 42664448);  //    614,400
  bf16_t* wo1t  = (bf16_t*)(ws + 43278848);  //    204,800
  float*  wkv2t = (float*)(ws + 43483648);   //  1,966,080
  bf16_t* wo2t  = (bf16_t*)(ws + 45449728);  //    204,800
  bf16_t* wff1t = (bf16_t*)(ws + 45654528);  //  1,638,400
  bf16_t* wff2t = (bf16_t*)(ws + 47292928);  //    819,200
  float*  lpart = (float*)(ws + 48112128);   //    262,144  f32 [2][8][4096]
  bf16_t* wq2th = (bf16_t*)(ws + 48374272);  //    204,800
  bf16_t* wq2tl = (bf16_t*)(ws + 48579072);  //    204,800
  bf16_t* famh  = (bf16_t*)(ws + 48783872);  //     18,432
  bf16_t* faml  = (bf16_t*)(ws + 48802304);  //     18,432
  bf16_t* k2h   = (bf16_t*)(ws + 48820736);  //     98,304
  bf16_t* k2l   = (bf16_t*)(ws + 48919040);  //     98,304
  bf16_t* v2t   = (bf16_t*)(ws + 49017344);  //     73,728  -> end 49,091,072
  // opart (f32, 2 splits) overlays x2+q2 (dead during flash+merge): [2][8][4096][40] f32 = 10,485,760
  float*  opart = (float*)(ws + 21495808);
  bf16_t* proj = (bf16_t*)(ws + 0);          // bf16 [4096][2560] (FF phase; overlays qkvb..h2lo)
  bf16_t* gg   = (bf16_t*)(ws + 21495808);   // bf16 [4096][1280] (FF phase; overlays x2,q2)

  float* xout = (float*)d_out;

  prep_kernel<<<2048, 256, 0, stream>>>(Wq1, Wk1, Wv1, Wo1, Wq2, Wk2, Wv2, Wo2, Wff1, Wff2, fam,
                                        wqkvt, wo1t, wkv2t, wo2t, wff1t, wff2t, wq2th, wq2tl,
                                        famh, faml);
  // --- attn1 (bf16/f16 MFMA flash) ---
  ln_kernel<bf16_t><<<1024, 256, 0, stream>>>(x, g1, b1, h1b);
  gemm_bf16_kernel<1><<<dim3(32,15), 256, 0, stream>>>(h1b, wqkvt, nullptr, nullptr, qkvb, 4096, 960, 320);
  repack_vt_kernel<<<dim3(64,8), 256, 0, stream>>>(qkvb, vtg);
  flash_self_kernel<<<dim3(512,2), 256, 0, stream>>>(qkvb, vtg, opart, lpart);
  merge_o1_kernel<<<5120, 256, 0, stream>>>(opart, lpart, o1a);
  gemm_bf16_32_kernel<0><<<dim3(128,5), 256, 0, stream>>>(o1a, wo1t, bo1, x, x2, 4096, 320, 320);
  // --- attn2 (sim2 path: fp32-emulated MFMA throughout) ---
  ln2_split_kernel<<<1024, 256, 0, stream>>>(x2, g2, b2, h2hi, h2lo);
  gemm3_32_kernel<<<dim3(128,5), 256, 0, stream>>>(h2hi, h2lo, wq2th, wq2tl, q2, 4096, 320, 320);
  kv2_dot_kernel<<<3080, 256, 0, stream>>>(ctx, wkv2t, kv2);
  kv2_post_kernel<<<336, 256, 0, stream>>>(kv2, k2h, k2l, v2t);
  attn_cross_kernel<<<512, 256, 0, stream>>>(q2, k2h, k2l, famh, faml, v2t, ufca, o2);
  gemm_bf16_32_kernel<0><<<dim3(128,5), 256, 0, stream>>>(o2, wo2t, bo2, x2, x3, 4096, 320, 320);
  // --- GEGLU FF ---
  ln_kernel<bf16_t><<<1024, 256, 0, stream>>>(x3, g3, b3, h3b);
  gemm_bf16_kernel<1><<<dim3(32,40), 256, 0, stream>>>(h3b, wff1t, bff1, nullptr, proj, 4096, 2560, 320);
  geglu_kernel<<<5120, 256, 0, stream>>>(proj, gg);
  gemm_bf16_32_kernel<0><<<dim3(128,5), 256, 0, stream>>>(gg, wff2t, bff2, x3, xout, 4096, 320, 1280);
}

// Round 12
// 315.763 us; speedup vs baseline: 1.2606x; 1.0054x over previous
//
#include <hip/hip_runtime.h>
#include <math.h>

typedef __bf16 bf16_t;
typedef __bf16 bf16x8 __attribute__((ext_vector_type(8)));
typedef __bf16 bf16x4 __attribute__((ext_vector_type(4)));
typedef float  f32x4  __attribute__((ext_vector_type(4)));
typedef _Float16 f16_t;
typedef _Float16 f16x4 __attribute__((ext_vector_type(4)));
typedef __fp16 hf16x2 __attribute__((ext_vector_type(2)));

static constexpr float ATT_SCALE = 0.15811388300841897f; // 40^-0.5
static constexpr float SC2 = 0.22811031f;                // ATT_SCALE * log2(e)
static constexpr float LOG2E = 1.4426950408889634f;

__device__ __forceinline__ bf16_t f2b(float f) {
  unsigned u = __float_as_uint(f);
  u = (u + 0x7fffu + ((u >> 16) & 1u)) >> 16;   // RNE
  unsigned short s = (unsigned short)u;
  bf16_t r;
  *(unsigned short*)&r = s;
  return r;
}
__device__ __forceinline__ float b2f(bf16_t b) {
  unsigned short s = *(const unsigned short*)&b;
  return __uint_as_float(((unsigned)s) << 16);
}
__device__ __forceinline__ void sto(float v, float* p)  { *p = v; }
__device__ __forceinline__ void sto(float v, bf16_t* p) { *p = f2b(v); }
__device__ __forceinline__ unsigned pkh2(float a, float b) {
  hf16x2 h = __builtin_amdgcn_cvt_pkrtz(a, b);
  return *(unsigned*)&h;
}

// =========================== weight repack ===========================
__global__ __launch_bounds__(256) void prep_kernel(
    const float* __restrict__ Wq1, const float* __restrict__ Wk1, const float* __restrict__ Wv1,
    const float* __restrict__ Wo1, const float* __restrict__ Wq2,
    const float* __restrict__ Wk2, const float* __restrict__ Wv2, const float* __restrict__ Wo2,
    const float* __restrict__ Wff1, const float* __restrict__ Wff2,
    const float* __restrict__ fam,
    bf16_t* __restrict__ wqkvt, bf16_t* __restrict__ wo1t, float* __restrict__ wkv2t,
    bf16_t* __restrict__ wo2t, bf16_t* __restrict__ wff1t, bf16_t* __restrict__ wff2t,
    bf16_t* __restrict__ wq2th, bf16_t* __restrict__ wq2tl,
    bf16_t* __restrict__ famh, bf16_t* __restrict__ faml)
{
  const int T1 = 960*320;
  const int T2 = T1 + 320*320;
  const int T3 = T2 + 768*640;
  const int T4 = T3 + 320*320;
  const int T5 = T4 + 2560*320;
  const int T6 = T5 + 320*1280;
  const int T7 = T6 + 320*320;
  const int T8 = T7 + 96*96;
  for (int i = blockIdx.x*256 + threadIdx.x; i < T8; i += gridDim.x*256) {
    if (i < T1) {
      int n = i / 320, k = i - n*320;
      float v = (n < 320) ? Wq1[k*320+n] * SC2
              : (n < 640) ? Wk1[k*320+n-320] : Wv1[k*320+n-640];
      wqkvt[i] = f2b(v);
    } else if (i < T2) {
      int e = i - T1; int n = e / 320, k = e - n*320;
      wo1t[e] = f2b(Wo1[k*320+n]);
    } else if (i < T3) {
      int e = i - T2; int n = e / 768, k = e - n*768;
      wkv2t[e] = (n < 320) ? Wk2[k*320+n] : Wv2[k*320+n-320];
    } else if (i < T4) {
      int e = i - T3; int n = e / 320, k = e - n*320;
      wo2t[e] = f2b(Wo2[k*320+n]);
    } else if (i < T5) {
      int e = i - T4; int n = e / 320, k = e - n*320;
      wff1t[e] = f2b(Wff1[(size_t)k*2560+n]);
    } else if (i < T6) {
      int e = i - T5; int n = e / 1280, k = e - n*1280;
      wff2t[e] = f2b(Wff2[k*320+n]);
    } else if (i < T7) {
      int e = i - T6; int n = e / 320, k = e - n*320;
      float v = Wq2[k*320+n];
      bf16_t h = f2b(v);
      wq2th[e] = h;
      wq2tl[e] = f2b(v - b2f(h));
    } else {
      int e = i - T7; int d = e / 96, k = e - d*96;
      float v = (d < 77 && k < 77) ? fam[d*77 + k] : 0.f;
      bf16_t h = f2b(v);
      famh[e] = h;
      faml[e] = f2b(v - b2f(h));
    }
  }
}

// =========================== LayerNorm ===========================
template<typename OT>
__global__ __launch_bounds__(256) void ln_kernel(
    const float* __restrict__ x, const float* __restrict__ g, const float* __restrict__ b,
    OT* __restrict__ out)
{
  const int lane = threadIdx.x & 63;
  const int row = blockIdx.x * 4 + (threadIdx.x >> 6);
  const float* xr = x + (size_t)row * 320;
  float v[5], s = 0.f, s2 = 0.f;
#pragma unroll
  for (int i = 0; i < 5; i++) { v[i] = xr[lane + i*64]; s += v[i]; s2 += v[i]*v[i]; }
#pragma unroll
  for (int o = 32; o; o >>= 1) { s += __shfl_xor(s, o); s2 += __shfl_xor(s2, o); }
  float mu = s * (1.f/320.f);
  float rs = rsqrtf(fmaxf(s2*(1.f/320.f) - mu*mu, 0.f) + 1e-5f);
#pragma unroll
  for (int i = 0; i < 5; i++) {
    int c = lane + i*64;
    sto((v[i]-mu)*rs*g[c] + b[c], &out[(size_t)row*320 + c]);
  }
}

// LayerNorm writing hi/lo bf16 split
__global__ __launch_bounds__(256) void ln2_split_kernel(
    const float* __restrict__ x, const float* __restrict__ g, const float* __restrict__ b,
    bf16_t* __restrict__ hi, bf16_t* __restrict__ lo)
{
  const int lane = threadIdx.x & 63;
  const int row = blockIdx.x * 4 + (threadIdx.x >> 6);
  const float* xr = x + (size_t)row * 320;
  float v[5], s = 0.f, s2 = 0.f;
#pragma unroll
  for (int i = 0; i < 5; i++) { v[i] = xr[lane + i*64]; s += v[i]; s2 += v[i]*v[i]; }
#pragma unroll
  for (int o = 32; o; o >>= 1) { s += __shfl_xor(s, o); s2 += __shfl_xor(s2, o); }
  float mu = s * (1.f/320.f);
  float rs = rsqrtf(fmaxf(s2*(1.f/320.f) - mu*mu, 0.f) + 1e-5f);
#pragma unroll
  for (int i = 0; i < 5; i++) {
    int c = lane + i*64;
    float y = (v[i]-mu)*rs*g[c] + b[c];
    bf16_t h = f2b(y);
    hi[(size_t)row*320 + c] = h;
    lo[(size_t)row*320 + c] = f2b(y - b2f(h));
  }
}

// =========================== kv2 dot-product GEMM ===========================
__global__ __launch_bounds__(256) void kv2_dot_kernel(
    const float* __restrict__ ctx, const float* __restrict__ wkv2t, float* __restrict__ kv2)
{
  const int gid = blockIdx.x*16 + (threadIdx.x >> 4);
  const int q = threadIdx.x & 15;
  const int m = gid / 640, n = gid - m*640;
  const float4* a = (const float4*)(ctx + (size_t)m*768);
  const float4* b = (const float4*)(wkv2t + (size_t)n*768);
  float acc = 0.f;
#pragma unroll
  for (int i = 0; i < 12; i++) {
    float4 av = a[i*16+q], bv = b[i*16+q];
    acc += av.x*bv.x + av.y*bv.y + av.z*bv.z + av.w*bv.w;
  }
#pragma unroll
  for (int o = 8; o; o >>= 1) acc += __shfl_xor(acc, o);
  if (q == 0) kv2[(size_t)m*640 + n] = acc;
}

// =========================== kv2 post: K2 hi/lo and V^T ===========================
__global__ __launch_bounds__(256) void kv2_post_kernel(
    const float* __restrict__ kv2, bf16_t* __restrict__ k2h, bf16_t* __restrict__ k2l,
    bf16_t* __restrict__ v2t)
{
  const int NK = 8*96*64;
  const int NV = 8*48*96;
  int i = blockIdx.x*256 + threadIdx.x;
  if (i < NK) {
    int h = i / (96*64), r = i - h*96*64, j = r >> 6, d = r & 63;
    float v = (j < 77 && d < 40) ? kv2[(size_t)j*640 + h*40 + d] : 0.f;
    bf16_t hh = f2b(v);
    k2h[i] = hh;
    k2l[i] = f2b(v - b2f(hh));
  } else if (i < NK + NV) {
    int e = i - NK;
    int h = e / (48*96), r = e - h*48*96, d = r / 96, j = r - d*96;
    v2t[e] = f2b((d < 40 && j < 77) ? kv2[(size_t)j*640 + 320 + h*40 + d] : 0.f);
  }
}

// =========================== V^T repack (self-attn): f16, 48 rows, row 40 = ones ===========================
__global__ __launch_bounds__(256) void repack_vt_kernel(
    const bf16_t* __restrict__ qkvb, f16_t* __restrict__ vtg)
{
  __shared__ f16_t T[64*44];
  const int tid = threadIdx.x;
  const int t0 = blockIdx.x * 64, h = blockIdx.y;
  for (int e = tid; e < 320; e += 256) {
    int t = e / 5, c8 = (e - t*5) * 8;
    bf16x8 v = *(const bf16x8*)(qkvb + (size_t)(t0+t)*960 + 640 + h*40 + c8);
    f16_t* dst = &T[t*44 + c8];
#pragma unroll
    for (int j = 0; j < 8; j++) dst[j] = (f16_t)b2f(v[j]);
  }
  __syncthreads();
  for (int e = tid; e < 320; e += 256) {
    int d = e >> 3, t8 = (e & 7) * 8;
    f16_t* dst = vtg + ((size_t)h*48 + d)*4096 + t0 + t8;
#pragma unroll
    for (int j = 0; j < 8; j++) dst[j] = T[(t8+j)*44 + d];
  }
  for (int e = tid; e < 512; e += 256) {
    int r = 40 + (e >> 6), t = e & 63;
    vtg[((size_t)h*48 + r)*4096 + t0 + t] = (r == 40) ? (f16_t)1.0f : (f16_t)0.0f;
  }
}

// =========================== bf16/f16 MFMA flash self-attention (v6: batched prefetch) ===========================
// grid (512, 2): blockIdx.x = qb*8 + h (XCD swizzle). ALL next-iter loads (K + 3xV) issued
// back-to-back at the top of each iteration, consumed one iteration later -> single drained
// waitcnt per iter instead of per-load serialization.
__global__ __launch_bounds__(256, 4) void flash_self_kernel(
    const bf16_t* __restrict__ qkvb, const f16_t* __restrict__ vtg,
    float* __restrict__ opart, float* __restrict__ lpart)
{
  __shared__ float Red[6144];      // 24 KB, two-pass epilogue
  const int tid = threadIdx.x;
  const int w = tid >> 6, lane = tid & 63;
  const int ln = lane & 15, qd = lane >> 4;
  const int h = blockIdx.x & 7;
  const int q0 = (blockIdx.x >> 3) * 64;
  const int split = blockIdx.y;

  bf16x8 zero8 = {};
  bf16x8 bq[4][2];
#pragma unroll
  for (int nt = 0; nt < 4; nt++) {
    const bf16_t* qp = qkvb + (size_t)(q0 + nt*16 + ln)*960 + h*40;
    bq[nt][0] = *(const bf16x8*)(qp + qd*8);
    bq[nt][1] = (qd == 0) ? *(const bf16x8*)(qp + 32) : zero8;
  }

  f32x4 zero4 = {0.f,0.f,0.f,0.f};
  f32x4 oacc[3][4];
#pragma unroll
  for (int a = 0; a < 3; a++)
#pragma unroll
    for (int b = 0; b < 4; b++) oacc[a][b] = zero4;

  const bf16_t* kbase = qkvb + 320 + h*40 + (size_t)(w*16 + ln)*960;
  const f16_t*  vrow  = vtg + (size_t)h*48*4096 + (size_t)ln*4096 + w*16 + qd*4;

  // preload K and V for tile 0
  const bf16_t* kp0 = kbase + (size_t)(split*2048)*960;
  bf16x8 ka0 = *(const bf16x8*)(kp0 + qd*8);
  bf16x8 ka1 = (qd == 0) ? *(const bf16x8*)(kp0 + 32) : zero8;
  f16x4 va[3];
#pragma unroll
  for (int dt = 0; dt < 3; dt++)
    va[dt] = *(const f16x4*)(vrow + (size_t)dt*16*4096 + split*2048);

  for (int kt = 0; kt < 32; kt++) {
    int k0 = split*2048 + kt*64;
    // --- batched prefetch of next tile: 2 K loads + 3 V loads, issued together ---
    bf16x8 nka0 = zero8, nka1 = zero8;
    f16x4 nva[3] = {};
    if (kt < 31) {
      const bf16_t* kpn = kbase + (size_t)(k0 + 64)*960;
      nka0 = *(const bf16x8*)(kpn + qd*8);
      if (qd == 0) nka1 = *(const bf16x8*)(kpn + 32);
#pragma unroll
      for (int dt = 0; dt < 3; dt++)
        nva[dt] = *(const f16x4*)(vrow + (size_t)dt*16*4096 + k0 + 64);
    }

    f16x4 pb[4];
#pragma unroll
    for (int nt = 0; nt < 4; nt++) {
      f32x4 s = __builtin_amdgcn_mfma_f32_16x16x32_bf16(ka0, bq[nt][0], zero4, 0, 0, 0);
      s = __builtin_amdgcn_mfma_f32_16x16x32_bf16(ka1, bq[nt][1], s, 0, 0, 0);
      uint2 u;
      u.x = pkh2(__builtin_amdgcn_exp2f(s[0]), __builtin_amdgcn_exp2f(s[1]));
      u.y = pkh2(__builtin_amdgcn_exp2f(s[2]), __builtin_amdgcn_exp2f(s[3]));
      pb[nt] = *(f16x4*)&u;
    }
#pragma unroll
    for (int dt = 0; dt < 3; dt++)
#pragma unroll
      for (int nt = 0; nt < 4; nt++)
        oacc[dt][nt] = __builtin_amdgcn_mfma_f32_16x16x16f16(va[dt], pb[nt], oacc[dt][nt], 0, 0, 0);

    ka0 = nka0;
    ka1 = nka1;
#pragma unroll
    for (int dt = 0; dt < 3; dt++) va[dt] = nva[dt];
  }

  // ---- epilogue: two-pass cross-wave (key-slice) reduction via LDS ----
  float* obase = opart + ((size_t)(split*8 + h)*4096 + q0)*40;
  for (int np = 0; np < 2; np++) {
    __syncthreads();
#pragma unroll
    for (int e = 0; e < 2; e++) {
      int nt = np*2 + e;
#pragma unroll
      for (int dt = 0; dt < 3; dt++)
        *(f32x4*)&Red[((w*2 + e)*3 + dt)*256 + ln*16 + qd*4] = oacc[dt][nt];
    }
    __syncthreads();
    int e = tid >> 7;
    int lq = (tid >> 3) & 15;
    int dbase = tid & 7;
#pragma unroll
    for (int i = 0; i < 5; i++) {
      int d = dbase + i*8;
      int dt = d >> 4, drow = d & 15;
      float v = Red[((0*2+e)*3 + dt)*256 + lq*16 + drow]
              + Red[((1*2+e)*3 + dt)*256 + lq*16 + drow]
              + Red[((2*2+e)*3 + dt)*256 + lq*16 + drow]
              + Red[((3*2+e)*3 + dt)*256 + lq*16 + drow];
      obase[(size_t)((np*2+e)*16 + lq)*40 + d] = v;
    }
    if (dbase == 0) {
      float l = Red[((0*2+e)*3 + 2)*256 + lq*16 + 8]
              + Red[((1*2+e)*3 + 2)*256 + lq*16 + 8]
              + Red[((2*2+e)*3 + 2)*256 + lq*16 + 8]
              + Red[((3*2+e)*3 + 2)*256 + lq*16 + 8];
      lpart[(size_t)(split*8 + h)*4096 + q0 + (np*2+e)*16 + lq] = l;
    }
  }
}

// =========================== merge K-split partials (2 splits, f32 opart) ===========================
__global__ __launch_bounds__(256) void merge_o1_kernel(
    const float* __restrict__ op, const float* __restrict__ lp, bf16_t* __restrict__ o1a)
{
  int i = blockIdx.x*256 + threadIdx.x;
  int q = i / 320, c = i - q*320;
  int h = c / 40, d = c - h*40;
  size_t base = ((size_t)h*4096 + q)*40 + d;
  float l = lp[h*4096 + q] + lp[32768 + h*4096 + q];
  float o = op[base] + op[base + 1310720];
  o1a[i] = f2b(o / l);
}

// =========================== cross-attention (all-MFMA, single-pass, no barriers; XCD swizzle) ===========================
__global__ __launch_bounds__(256) void attn_cross_kernel(
    const float* __restrict__ q2, const bf16_t* __restrict__ k2h, const bf16_t* __restrict__ k2l,
    const bf16_t* __restrict__ famh, const bf16_t* __restrict__ faml,
    const bf16_t* __restrict__ v2t, const int* __restrict__ use_fca,
    bf16_t* __restrict__ o2)
{
  __shared__ bf16_t SMh[4][16*96];
  __shared__ bf16_t SMl[4][16*96];
  __shared__ bf16_t PAs[4][16*96];
  const int tid = threadIdx.x;
  const int w = tid >> 6, lane = tid & 63;
  const int ln = lane & 15, qd = lane >> 4;
  const int h = blockIdx.x & 7;
  const int q0 = (blockIdx.x >> 3)*64 + w*16;
  const int fca = use_fca[0];
  bf16_t* smh = SMh[w];
  bf16_t* sml = SMl[w];
  bf16_t* pa  = PAs[w];

  {
    bf16x4 z = {};
    int q = lane >> 2, c = 80 + (lane & 3)*4;
    *(bf16x4*)&smh[q*96 + c] = z;
    *(bf16x4*)&sml[q*96 + c] = z;
    *(bf16x4*)&pa [q*96 + c] = z;
  }

  bf16x8 zero8 = {};
  bf16x8 aqh0, aql0, aqh1 = zero8, aql1 = zero8;
  {
    const float* qp = q2 + (size_t)(q0 + ln)*320 + h*40;
    float4 v0 = *(const float4*)(qp + qd*8);
    float4 v1 = *(const float4*)(qp + qd*8 + 4);
    float qv[8] = {v0.x,v0.y,v0.z,v0.w,v1.x,v1.y,v1.z,v1.w};
#pragma unroll
    for (int i = 0; i < 8; i++) {
      bf16_t hh = f2b(qv[i]);
      aqh0[i] = hh; aql0[i] = f2b(qv[i] - b2f(hh));
    }
    if (qd == 0) {
      float4 u0 = *(const float4*)(qp + 32);
      float4 u1 = *(const float4*)(qp + 36);
      float uv[8] = {u0.x,u0.y,u0.z,u0.w,u1.x,u1.y,u1.z,u1.w};
#pragma unroll
      for (int i = 0; i < 8; i++) {
        bf16_t hh = f2b(uv[i]);
        aqh1[i] = hh; aql1[i] = f2b(uv[i] - b2f(hh));
      }
    }
  }

  f32x4 zero4 = {0.f,0.f,0.f,0.f};
  float ss[5][4];
#pragma unroll
  for (int nt = 0; nt < 5; nt++) {
    const bf16_t* kb = k2h + ((size_t)h*96 + nt*16 + ln)*64 + qd*8;
    const bf16_t* kl = k2l + ((size_t)h*96 + nt*16 + ln)*64 + qd*8;
    bf16x8 kh0 = *(const bf16x8*)kb;
    bf16x8 kh1 = *(const bf16x8*)(kb + 32);
    bf16x8 kl0 = *(const bf16x8*)kl;
    bf16x8 kl1 = *(const bf16x8*)(kl + 32);
    f32x4 s;
    s = __builtin_amdgcn_mfma_f32_16x16x32_bf16(aqh0, kl0, zero4, 0, 0, 0);
    s = __builtin_amdgcn_mfma_f32_16x16x32_bf16(aql0, kh0, s, 0, 0, 0);
    s = __builtin_amdgcn_mfma_f32_16x16x32_bf16(aqh0, kh0, s, 0, 0, 0);
    s = __builtin_amdgcn_mfma_f32_16x16x32_bf16(aqh1, kl1, s, 0, 0, 0);
    s = __builtin_amdgcn_mfma_f32_16x16x32_bf16(aql1, kh1, s, 0, 0, 0);
    s = __builtin_amdgcn_mfma_f32_16x16x32_bf16(aqh1, kh1, s, 0, 0, 0);
#pragma unroll
    for (int r = 0; r < 4; r++) {
      float sv = s[r] * ATT_SCALE;
      ss[nt][r] = sv;
      bf16_t hh = f2b(sv);
      smh[(qd*4 + r)*96 + nt*16 + ln] = hh;
      sml[(qd*4 + r)*96 + nt*16 + ln] = f2b(sv - b2f(hh));
    }
  }

  f32x4 facc[5];
#pragma unroll
  for (int nt = 0; nt < 5; nt++) facc[nt] = zero4;
#pragma unroll
  for (int c = 0; c < 3; c++) {
    bf16x8 sah = *(const bf16x8*)&smh[ln*96 + c*32 + qd*8];
    bf16x8 sal = *(const bf16x8*)&sml[ln*96 + c*32 + qd*8];
#pragma unroll
    for (int nt = 0; nt < 5; nt++) {
      bf16x8 fh8 = *(const bf16x8*)(famh + ((size_t)(nt*16 + ln))*96 + c*32 + qd*8);
      bf16x8 fl8 = *(const bf16x8*)(faml + ((size_t)(nt*16 + ln))*96 + c*32 + qd*8);
      facc[nt] = __builtin_amdgcn_mfma_f32_16x16x32_bf16(sah, fl8, facc[nt], 0, 0, 0);
      facc[nt] = __builtin_amdgcn_mfma_f32_16x16x32_bf16(sal, fh8, facc[nt], 0, 0, 0);
      facc[nt] = __builtin_amdgcn_mfma_f32_16x16x32_bf16(sah, fh8, facc[nt], 0, 0, 0);
    }
  }

  float pr[5][4];
  if (fca) {
    float fwv[5][4], fm[4];
#pragma unroll
    for (int nt = 0; nt < 5; nt++)
#pragma unroll
      for (int r = 0; r < 4; r++) fwv[nt][r] = fminf(fabsf(facc[nt][r]), 1.f);
#pragma unroll
    for (int r = 0; r < 4; r++) {
      float m = fmaxf(fmaxf(fwv[0][r], fwv[1][r]), fmaxf(fwv[2][r], fmaxf(fwv[3][r], fwv[4][r])));
#pragma unroll
      for (int o = 8; o; o >>= 1) m = fmaxf(m, __shfl_xor(m, o));
      fm[r] = m;
    }
#pragma unroll
    for (int nt = 0; nt < 5; nt++)
#pragma unroll
      for (int r = 0; r < 4; r++) {
        float lg = ss[nt][r] - ((fwv[nt][r] > 0.6f*(fm[r] + 1e-6f)) ? 0.f : 50.f);
        pr[nt][r] = __builtin_amdgcn_exp2f(lg * LOG2E);
      }
  } else {
#pragma unroll
    for (int nt = 0; nt < 5; nt++)
#pragma unroll
      for (int r = 0; r < 4; r++)
        pr[nt][r] = __builtin_amdgcn_exp2f(ss[nt][r] * LOG2E);
  }
  if (ln >= 13) {
#pragma unroll
    for (int r = 0; r < 4; r++) pr[4][r] = 0.f;
  }
  float l_[4] = {0.f,0.f,0.f,0.f};
#pragma unroll
  for (int nt = 0; nt < 5; nt++)
#pragma unroll
    for (int r = 0; r < 4; r++) {
      l_[r] += pr[nt][r];
      pa[(qd*4 + r)*96 + nt*16 + ln] = f2b(pr[nt][r]);
    }
#pragma unroll
  for (int r = 0; r < 4; r++)
#pragma unroll
    for (int o = 8; o; o >>= 1) l_[r] += __shfl_xor(l_[r], o);

  f32x4 oacc[3];
#pragma unroll
  for (int nt = 0; nt < 3; nt++) oacc[nt] = zero4;
#pragma unroll
  for (int c = 0; c < 3; c++) {
    bf16x8 paf = *(const bf16x8*)&pa[ln*96 + c*32 + qd*8];
#pragma unroll
    for (int nt = 0; nt < 3; nt++) {
      bf16x8 vb = *(const bf16x8*)(v2t + ((size_t)h*48 + nt*16 + ln)*96 + c*32 + qd*8);
      oacc[nt] = __builtin_amdgcn_mfma_f32_16x16x32_bf16(paf, vb, oacc[nt], 0, 0, 0);
    }
  }
  float inv[4];
#pragma unroll
  for (int r = 0; r < 4; r++) inv[r] = 1.f / l_[r];
#pragma unroll
  for (int nt = 0; nt < 3; nt++) {
    int d = nt*16 + ln;
    if (d < 40) {
#pragma unroll
      for (int r = 0; r < 4; r++)
        o2[(size_t)(q0 + qd*4 + r)*320 + h*40 + d] = f2b(oacc[nt][r]*inv[r]);
    }
  }
}

// =========================== bf16 MFMA GEMM 128x64 ===========================
template<int OUT_BF16>
__global__ __launch_bounds__(256) void gemm_bf16_kernel(
    const bf16_t* __restrict__ A, const bf16_t* __restrict__ Bt,
    const float* __restrict__ bias, const float* __restrict__ resid,
    void* __restrict__ Cout, int M, int N, int K)
{
  __shared__ bf16_t As[128][72];
  __shared__ bf16_t Bs[64][72];
  const int tid = threadIdx.x;
  const int m0 = blockIdx.x * 128, n0 = blockIdx.y * 64;
  const int w = tid >> 6, lane = tid & 63;
  const int wr = w >> 1, wc = w & 1;
  const int ln = lane & 15, qd = lane >> 4;
  f32x4 zero = {0.f, 0.f, 0.f, 0.f};
  f32x4 acc[4][2];
#pragma unroll
  for (int a = 0; a < 4; a++)
#pragma unroll
    for (int b = 0; b < 2; b++) acc[a][b] = zero;

  for (int k0 = 0; k0 < K; k0 += 64) {
    __syncthreads();
#pragma unroll
    for (int i = 0; i < 4; i++) {
      int vid = tid + i*256;
      int r = vid >> 3, c8 = (vid & 7) * 8;
      *(bf16x8*)&As[r][c8] = *(const bf16x8*)(A + (size_t)(m0+r)*K + k0 + c8);
    }
#pragma unroll
    for (int i = 0; i < 2; i++) {
      int vid = tid + i*256;
      int r = vid >> 3, c8 = (vid & 7) * 8;
      *(bf16x8*)&Bs[r][c8] = *(const bf16x8*)(Bt + (size_t)(n0+r)*K + k0 + c8);
    }
    __syncthreads();
#pragma unroll
    for (int c = 0; c < 2; c++) {
      bf16x8 af[4], bfr[2];
#pragma unroll
      for (int mt = 0; mt < 4; mt++)
        af[mt] = *(const bf16x8*)&As[wr*64 + mt*16 + ln][c*32 + qd*8];
#pragma unroll
      for (int nt = 0; nt < 2; nt++)
        bfr[nt] = *(const bf16x8*)&Bs[wc*32 + nt*16 + ln][c*32 + qd*8];
#pragma unroll
      for (int mt = 0; mt < 4; mt++)
#pragma unroll
        for (int nt = 0; nt < 2; nt++)
          acc[mt][nt] = __builtin_amdgcn_mfma_f32_16x16x32_bf16(af[mt], bfr[nt], acc[mt][nt], 0, 0, 0);
    }
  }
#pragma unroll
  for (int mt = 0; mt < 4; mt++)
#pragma unroll
    for (int nt = 0; nt < 2; nt++)
#pragma unroll
      for (int r = 0; r < 4; r++) {
        int gm = m0 + wr*64 + mt*16 + qd*4 + r;
        int gn = n0 + wc*32 + nt*16 + ln;
        float v = acc[mt][nt][r];
        if (bias)  v += bias[gn];
        if (resid) v += resid[(size_t)gm*N + gn];
        if (OUT_BF16) sto(v, &((bf16_t*)Cout)[(size_t)gm*N + gn]);
        else          sto(v, &((float*)Cout)[(size_t)gm*N + gn]);
      }
}

// =========================== bf16 MFMA GEMM 32x64 (4x block count for narrow GEMMs) ===========================
template<int OUT_BF16>
__global__ __launch_bounds__(256) void gemm_bf16_32_kernel(
    const bf16_t* __restrict__ A, const bf16_t* __restrict__ Bt,
    const float* __restrict__ bias, const float* __restrict__ resid,
    void* __restrict__ Cout, int M, int N, int K)
{
  __shared__ bf16_t As[32][72];
  __shared__ bf16_t Bs[64][72];
  const int tid = threadIdx.x;
  const int m0 = blockIdx.x * 32, n0 = blockIdx.y * 64;
  const int w = tid >> 6, lane = tid & 63;
  const int wr = w >> 1, wc = w & 1;
  const int ln = lane & 15, qd = lane >> 4;
  f32x4 zero = {0.f, 0.f, 0.f, 0.f};
  f32x4 acc[2];
  acc[0] = zero; acc[1] = zero;

  for (int k0 = 0; k0 < K; k0 += 64) {
    __syncthreads();
    {
      int r = tid >> 3, c8 = (tid & 7) * 8;
      *(bf16x8*)&As[r][c8] = *(const bf16x8*)(A + (size_t)(m0+r)*K + k0 + c8);
    }
#pragma unroll
    for (int i = 0; i < 2; i++) {
      int vid = tid + i*256;
      int r = vid >> 3, c8 = (vid & 7) * 8;
      *(bf16x8*)&Bs[r][c8] = *(const bf16x8*)(Bt + (size_t)(n0+r)*K + k0 + c8);
    }
    __syncthreads();
#pragma unroll
    for (int c = 0; c < 2; c++) {
      bf16x8 af = *(const bf16x8*)&As[wr*16 + ln][c*32 + qd*8];
#pragma unroll
      for (int nt = 0; nt < 2; nt++) {
        bf16x8 bfr = *(const bf16x8*)&Bs[wc*32 + nt*16 + ln][c*32 + qd*8];
        acc[nt] = __builtin_amdgcn_mfma_f32_16x16x32_bf16(af, bfr, acc[nt], 0, 0, 0);
      }
    }
  }
#pragma unroll
  for (int nt = 0; nt < 2; nt++)
#pragma unroll
    for (int r = 0; r < 4; r++) {
      int gm = m0 + wr*16 + qd*4 + r;
      int gn = n0 + wc*32 + nt*16 + ln;
      float v = acc[nt][r];
      if (bias)  v += bias[gn];
      if (resid) v += resid[(size_t)gm*N + gn];
      if (OUT_BF16) sto(v, &((bf16_t*)Cout)[(size_t)gm*N + gn]);
      else          sto(v, &((float*)Cout)[(size_t)gm*N + gn]);
    }
}

// =========================== 3-term bf16 MFMA GEMM (fp32 emulation), 32x64 tile ===========================
__global__ __launch_bounds__(256) void gemm3_32_kernel(
    const bf16_t* __restrict__ Ah, const bf16_t* __restrict__ Al,
    const bf16_t* __restrict__ Bth, const bf16_t* __restrict__ Btl,
    float* __restrict__ C, int M, int N, int K)
{
  __shared__ bf16_t Ash[32][72];
  __shared__ bf16_t Asl[32][72];
  __shared__ bf16_t Bsh[64][72];
  __shared__ bf16_t Bsl[64][72];
  const int tid = threadIdx.x;
  const int m0 = blockIdx.x * 32, n0 = blockIdx.y * 64;
  const int w = tid >> 6, lane = tid & 63;
  const int wr = w >> 1, wc = w & 1;
  const int ln = lane & 15, qd = lane >> 4;
  f32x4 zero = {0.f, 0.f, 0.f, 0.f};
  f32x4 acc[2];
  acc[0] = zero; acc[1] = zero;

  for (int k0 = 0; k0 < K; k0 += 64) {
    __syncthreads();
    {
      int r = tid >> 3, c8 = (tid & 7) * 8;
      *(bf16x8*)&Ash[r][c8] = *(const bf16x8*)(Ah + (size_t)(m0+r)*K + k0 + c8);
      *(bf16x8*)&Asl[r][c8] = *(const bf16x8*)(Al + (size_t)(m0+r)*K + k0 + c8);
    }
#pragma unroll
    for (int i = 0; i < 2; i++) {
      int vid = tid + i*256;
      int r = vid >> 3, c8 = (vid & 7) * 8;
      *(bf16x8*)&Bsh[r][c8] = *(const bf16x8*)(Bth + (size_t)(n0+r)*K + k0 + c8);
      *(bf16x8*)&Bsl[r][c8] = *(const bf16x8*)(Btl + (size_t)(n0+r)*K + k0 + c8);
    }
    __syncthreads();
#pragma unroll
    for (int c = 0; c < 2; c++) {
      bf16x8 afh = *(const bf16x8*)&Ash[wr*16 + ln][c*32 + qd*8];
      bf16x8 afl = *(const bf16x8*)&Asl[wr*16 + ln][c*32 + qd*8];
#pragma unroll
      for (int nt = 0; nt < 2; nt++) {
        bf16x8 bfh = *(const bf16x8*)&Bsh[wc*32 + nt*16 + ln][c*32 + qd*8];
        bf16x8 bfl = *(const bf16x8*)&Bsl[wc*32 + nt*16 + ln][c*32 + qd*8];
        acc[nt] = __builtin_amdgcn_mfma_f32_16x16x32_bf16(afh, bfl, acc[nt], 0, 0, 0);
        acc[nt] = __builtin_amdgcn_mfma_f32_16x16x32_bf16(afl, bfh, acc[nt], 0, 0, 0);
        acc[nt] = __builtin_amdgcn_mfma_f32_16x16x32_bf16(afh, bfh, acc[nt], 0, 0, 0);
      }
    }
  }
#pragma unroll
  for (int nt = 0; nt < 2; nt++)
#pragma unroll
    for (int r = 0; r < 4; r++) {
      int gm = m0 + wr*16 + qd*4 + r;
      int gn = n0 + wc*32 + nt*16 + ln;
      C[(size_t)gm*N + gn] = acc[nt][r];
    }
}

// =========================== GEGLU ===========================
__global__ __launch_bounds__(256) void geglu_kernel(
    const bf16_t* __restrict__ proj, bf16_t* __restrict__ gg)
{
  int idx = blockIdx.x * 256 + threadIdx.x;
  int m = idx / 320, c4 = (idx - m*320) * 4;
  bf16x4 a = *(const bf16x4*)(proj + (size_t)m*2560 + c4);
  bf16x4 g = *(const bf16x4*)(proj + (size_t)m*2560 + 1280 + c4);
  bf16x4 r;
#pragma unroll
  for (int i = 0; i < 4; i++) {
    float gf = b2f(g[i]);
    float ge = 0.5f * gf * (1.f + erff(gf * 0.70710678118654752f));
    r[i] = f2b(b2f(a[i]) * ge);
  }
  *(bf16x4*)(gg + (size_t)m*1280 + c4) = r;
}

// =========================== launch ===========================
extern "C" void kernel_launch(void* const* d_in, const int* in_sizes, int n_in,
                              void* d_out, int out_size, void* d_ws, size_t ws_size,
                              hipStream_t stream)
{
  const float* x    = (const float*)d_in[0];
  const float* ctx  = (const float*)d_in[1];
  const float* fam  = (const float*)d_in[2];
  const float* g1   = (const float*)d_in[3];
  const float* b1   = (const float*)d_in[4];
  const float* g2   = (const float*)d_in[5];
  const float* b2   = (const float*)d_in[6];
  const float* g3   = (const float*)d_in[7];
  const float* b3   = (const float*)d_in[8];
  const float* Wq1  = (const float*)d_in[9];
  const float* Wk1  = (const float*)d_in[10];
  const float* Wv1  = (const float*)d_in[11];
  const float* Wo1  = (const float*)d_in[12];
  const float* bo1  = (const float*)d_in[13];
  const float* Wq2  = (const float*)d_in[14];
  const float* Wk2  = (const float*)d_in[15];
  const float* Wv2  = (const float*)d_in[16];
  const float* Wo2  = (const float*)d_in[17];
  const float* bo2  = (const float*)d_in[18];
  const float* Wff1 = (const float*)d_in[19];
  const float* bff1 = (const float*)d_in[20];
  const float* Wff2 = (const float*)d_in[21];
  const float* bff2 = (const float*)d_in[22];
  const int*   ufca = (const int*)d_in[23];

  char* ws = (char*)d_ws;
  bf16_t* qkvb = (bf16_t*)(ws + 0);          //  7,864,320  bf16 [4096][960] (Q pre-scaled)
  f16_t*  vtg  = (f16_t*)(ws + 7864320);     //  3,145,728  f16 [8][48][4096] (row40=1)
  bf16_t* o1a  = (bf16_t*)(ws + 11010048);   //  2,621,440  bf16 [4096][320]
  bf16_t* h1b  = (bf16_t*)(ws + 13631488);   //  2,621,440
  bf16_t* h2hi = (bf16_t*)(ws + 16252928);   //  2,621,440
  bf16_t* h2lo = (bf16_t*)(ws + 18874368);   //  2,621,440
  float*  x2   = (float*)(ws + 21495808);    //  5,242,880
  float*  q2   = (float*)(ws + 26738688);    //  5,242,880
  float*  kv2  = (float*)(ws + 31981568);    //    197,120
  bf16_t* o2   = (bf16_t*)(ws + 32178688);   //  2,621,440
  float*  x3   = (float*)(ws + 34800128);    //  5,242,880
  bf16_t* h3b  = (bf16_t*)(ws + 40043008);   //  2,621,440
  bf16_t* wqkvt = (bf16_t*)(ws + 42664448);  //    614,400
  bf16_t* wo1t  = (bf16_t*)(ws + 43278848);  //    204,800
  float*  wkv2t = (float*)(ws + 43483648);   //  1,966,080
  bf16_t* wo2t  = (bf16_t*)(ws + 45449728);  //    204,800
  bf16_t* wff1t = (bf16_t*)(ws + 45654528);  //  1,638,400
  bf16_t* wff2t = (bf16_t*)(ws + 47292928);  //    819,200
  float*  lpart = (float*)(ws + 48112128);   //    262,144  f32 [2][8][4096]
  bf16_t* wq2th = (bf16_t*)(ws + 48374272);  //    204,800
  bf16_t* wq2tl = (bf16_t*)(ws + 48579072);  //    204,800
  bf16_t* famh  = (bf16_t*)(ws + 48783872);  //     18,432
  bf16_t* faml  = (bf16_t*)(ws + 48802304);  //     18,432
  bf16_t* k2h   = (bf16_t*)(ws + 48820736);  //     98,304
  bf16_t* k2l   = (bf16_t*)(ws + 48919040);  //     98,304
  bf16_t* v2t   = (bf16_t*)(ws + 49017344);  //     73,728  -> end 49,091,072
  // opart (f32, 2 splits) overlays x2+q2 (dead during flash+merge): [2][8][4096][40] f32 = 10,485,760
  float*  opart = (float*)(ws + 21495808);
  bf16_t* proj = (bf16_t*)(ws + 0);          // bf16 [4096][2560] (FF phase; overlays qkvb..h2lo)
  bf16_t* gg   = (bf16_t*)(ws + 21495808);   // bf16 [4096][1280] (FF phase; overlays x2,q2)

  float* xout = (float*)d_out;

  prep_kernel<<<2048, 256, 0, stream>>>(Wq1, Wk1, Wv1, Wo1, Wq2, Wk2, Wv2, Wo2, Wff1, Wff2, fam,
                                        wqkvt, wo1t, wkv2t, wo2t, wff1t, wff2t, wq2th, wq2tl,
                                        famh, faml);
  // --- attn1 (bf16/f16 MFMA flash) ---
  ln_kernel<bf16_t><<<1024, 256, 0, stream>>>(x, g1, b1, h1b);
  gemm_bf16_kernel<1><<<dim3(32,15), 256, 0, stream>>>(h1b, wqkvt, nullptr, nullptr, qkvb, 4096, 960, 320);
  repack_vt_kernel<<<dim3(64,8), 256, 0, stream>>>(qkvb, vtg);
  flash_self_kernel<<<dim3(512,2), 256, 0, stream>>>(qkvb, vtg, opart, lpart);
  merge_o1_kernel<<<5120, 256, 0, stream>>>(opart, lpart, o1a);
  gemm_bf16_32_kernel<0><<<dim3(128,5), 256, 0, stream>>>(o1a, wo1t, bo1, x, x2, 4096, 320, 320);
  // --- attn2 (sim2 path: fp32-emulated MFMA throughout) ---
  ln2_split_kernel<<<1024, 256, 0, stream>>>(x2, g2, b2, h2hi, h2lo);
  gemm3_32_kernel<<<dim3(128,5), 256, 0, stream>>>(h2hi, h2lo, wq2th, wq2tl, q2, 4096, 320, 320);
  kv2_dot_kernel<<<3080, 256, 0, stream>>>(ctx, wkv2t, kv2);
  kv2_post_kernel<<<336, 256, 0, stream>>>(kv2, k2h, k2l, v2t);
  attn_cross_kernel<<<512, 256, 0, stream>>>(q2, k2h, k2l, famh, faml, v2t, ufca, o2);
  gemm_bf16_32_kernel<0><<<dim3(128,5), 256, 0, stream>>>(o2, wo2t, bo2, x2, x3, 4096, 320, 320);
  // --- GEGLU FF ---
  ln_kernel<bf16_t><<<1024, 256, 0, stream>>>(x3, g3, b3, h3b);
  gemm_bf16_kernel<1><<<dim3(32,40), 256, 0, stream>>>(h3b, wff1t, bff1, nullptr, proj, 4096, 2560, 320);
  geglu_kernel<<<5120, 256, 0, stream>>>(proj, gg);
  gemm_bf16_32_kernel<0><<<dim3(128,5), 256, 0, stream>>>(gg, wff2t, bff2, x3, xout, 4096, 320, 1280);
}